// Round 3
// baseline (25814.404 us; speedup 1.0000x reference)
//
#include <hip/hip_runtime.h>
#include <hip/hip_bf16.h>
#include <hip/hip_cooperative_groups.h>

namespace cg = cooperative_groups;

typedef unsigned short ushort_t;
typedef unsigned int   uint_t;

// Problem constants: T1=257, B=512, SD=128, AD=32, HS=512, SF=256, L=2
#define M_ALL 131584   // 257*512
#define M_SEQ 131072   // 256*512

// ---------- helpers ----------
__device__ __forceinline__ float bf2f(ushort_t u) {
    union { uint_t i; float f; } v; v.i = ((uint_t)u) << 16; return v.f;
}
__device__ __forceinline__ float asf(uint_t i) {
    union { uint_t u; float f; } v; v.u = i; return v.f;
}
__device__ __forceinline__ ushort_t f2bf(float f) {
    union { float f; uint_t i; } v; v.f = f;
    uint_t r = v.i + 0x7FFFu + ((v.i >> 16) & 1u);
    return (ushort_t)(r >> 16);
}
__device__ __forceinline__ float fsigm(float x) { return 1.f / (1.f + __expf(-x)); }
__device__ __forceinline__ float ftanh(float x) {
    x = fminf(15.f, fmaxf(-15.f, x));
    float e = __expf(2.f * x);
    return (e - 1.f) / (e + 1.f);
}

typedef __attribute__((ext_vector_type(8))) short  bfrag;   // 8 x bf16
typedef __attribute__((ext_vector_type(4))) float  ffrag;   // 4 x f32 accum

// stage 8 elements into LDS as bf16 (f32 source converts, bf16 source copies)
__device__ __forceinline__ void stage8(const float* p, ushort_t* dst) {
    const float4 a = *(const float4*)p;
    const float4 b = *(const float4*)(p + 4);
    bfrag v;
    v[0] = (short)f2bf(a.x); v[1] = (short)f2bf(a.y);
    v[2] = (short)f2bf(a.z); v[3] = (short)f2bf(a.w);
    v[4] = (short)f2bf(b.x); v[5] = (short)f2bf(b.y);
    v[6] = (short)f2bf(b.z); v[7] = (short)f2bf(b.w);
    *(bfrag*)dst = v;
}
__device__ __forceinline__ void stage8(const ushort_t* p, ushort_t* dst) {
    *(uint4*)dst = *(const uint4*)p;
}

// ---------- generic bf16 MFMA GEMM: C = act(A @ W^T + bias), C is bf16 ----------
// AMODE 0: plain A1 (stride K)
// AMODE 1: k<256 -> A1 stride 256 ; k>=256 -> A2 stride 32  (x = [sf, action])
// AMODE 2: k<256 -> A1 stride 256 ; k>=256 -> A2 stride 256 (xi = [sf, pred_next])
// W: (N,K) float32. b1/b2: float32.
template<int AMODE, int ACT, int NBIAS, typename TA1, typename TA2>
__global__ __launch_bounds__(256) void gemm_k(
    const TA1* __restrict__ A1, const TA2* __restrict__ A2,
    const float* __restrict__ W, const float* __restrict__ b1,
    const float* __restrict__ b2, ushort_t* __restrict__ C,
    int K, int N)
{
    __shared__ __align__(16) ushort_t As[64][40];
    __shared__ __align__(16) ushort_t Ws[64][40];

    const int tid  = threadIdx.x;
    const int m0   = blockIdx.x * 64;
    const int n0   = blockIdx.y * 64;
    const int lane = tid & 63;
    const int wv   = tid >> 6;
    const int wm   = (wv & 1) * 32;
    const int wn   = (wv >> 1) * 32;
    const int quad = lane >> 4;
    const int ln   = lane & 15;

    ffrag acc[2][2];
#pragma unroll
    for (int i = 0; i < 2; i++)
#pragma unroll
        for (int j = 0; j < 2; j++) acc[i][j] = (ffrag){0.f, 0.f, 0.f, 0.f};

    const int arow = tid >> 2;        // 0..63
    const int acol = (tid & 3) * 8;   // 0,8,16,24

    for (int k0 = 0; k0 < K; k0 += 32) {
        const int kk = k0 + acol;
        if (AMODE == 0) {
            stage8(A1 + (size_t)(m0 + arow) * K + kk, &As[arow][acol]);
        } else if (AMODE == 1) {
            if (kk < 256) stage8(A1 + (size_t)(m0 + arow) * 256 + kk, &As[arow][acol]);
            else          stage8(A2 + (size_t)(m0 + arow) * 32 + (kk - 256), &As[arow][acol]);
        } else {
            if (kk < 256) stage8(A1 + (size_t)(m0 + arow) * 256 + kk, &As[arow][acol]);
            else          stage8(A2 + (size_t)(m0 + arow) * 256 + (kk - 256), &As[arow][acol]);
        }
        stage8(W + (size_t)(n0 + arow) * K + kk, &Ws[arow][acol]);
        __syncthreads();

        bfrag af[2], bfv[2];
#pragma unroll
        for (int i = 0; i < 2; i++) af[i]  = *(const bfrag*)&As[wm + i * 16 + ln][quad * 8];
#pragma unroll
        for (int j = 0; j < 2; j++) bfv[j] = *(const bfrag*)&Ws[wn + j * 16 + ln][quad * 8];
#pragma unroll
        for (int i = 0; i < 2; i++)
#pragma unroll
            for (int j = 0; j < 2; j++)
                acc[i][j] = __builtin_amdgcn_mfma_f32_16x16x32_bf16(af[i], bfv[j], acc[i][j], 0, 0, 0);
        __syncthreads();
    }

#pragma unroll
    for (int j = 0; j < 2; j++) {
        const int n = n0 + wn + j * 16 + ln;
        float bias = b1[n];
        if (NBIAS == 2) bias += b2[n];
#pragma unroll
        for (int i = 0; i < 2; i++) {
#pragma unroll
            for (int r = 0; r < 4; r++) {
                const int m = m0 + wm + i * 16 + quad * 4 + r;
                float x = acc[i][j][r] + bias;
                if (ACT == 1) x = fmaxf(x, 0.f);
                C[(size_t)m * N + n] = f2bf(x);
            }
        }
    }
}

// ---------- weight prep: gate-interleaved transposed recurrent weights (f32 -> bf16) ----------
__global__ __launch_bounds__(256) void prep_k(
    const float* __restrict__ Whh0, const float* __restrict__ Wih1,
    const float* __restrict__ Whh1,
    const float* __restrict__ bih1, const float* __restrict__ bhh1,
    ushort_t* __restrict__ wt0, ushort_t* __restrict__ wt1,
    float* __restrict__ bias1)
{
    const int idx = blockIdx.x * 256 + threadIdx.x;
    const int stride = gridDim.x * 256;
    for (int e = idx; e < 262144; e += stride) {
        int k = e >> 10, q = e & 1023;
        int s = q & 1, u = (q >> 1) & 255;
        int j = ((q >> 9) << 9) + s * 256 + u;
        wt0[e] = f2bf(Whh0[j * 256 + k]);
    }
    for (int e = idx; e < 524288; e += stride) {
        int k = e >> 10, q = e & 1023;
        int s = q & 1, u = (q >> 1) & 255;
        int j = ((q >> 9) << 9) + s * 256 + u;
        wt1[e] = f2bf((k < 256) ? Wih1[j * 256 + k] : Whh1[j * 256 + (k - 256)]);
    }
    for (int e = idx; e < 1024; e += stride) {
        bias1[e] = bih1[e] + bhh1[e];
    }
}

// ---------- persistent cooperative LSTM scan chunk, layer-pipelined ----------
struct RecArgs {
    const ushort_t* xg0ck;   // x-part of layer0 gates for this chunk (incl. biases), bf16
    const int*      dones;   // (257,512) global int32
    const ushort_t* wt0;     // interleaved Whh0 (256,1024) bf16
    const ushort_t* wt1;     // interleaved [Wih1;Whh1] (512,1024) bf16
    const float*    bias1;
    float*          st;      // h0buf[2] | c0 | h1 | c1 : 5 * 131072 f32 (persistent)
    ushort_t*       outs;    // (257*512, 256) bf16
    int jc, jend, nsteps, init;
};

__global__ __launch_bounds__(256, 2) void rec_k(RecArgs a)
{
    cg::grid_group grid = cg::this_grid();
    __shared__ float xs[2][512];
    const int tid = threadIdx.x;
    const int bid = blockIdx.x;

    float* h0buf = a.st;
    float* c0    = a.st + 262144;
    float* h1    = a.st + 393216;
    float* c1    = a.st + 524288;

    if (a.init) {
        const int idx = bid * 256 + tid;
#pragma unroll
        for (int i = 0; i < 5; i++) a.st[idx + i * 131072] = 0.f;
        grid.sync();
    }

    for (int j = a.jc; j < a.jend; ++j) {
        if (bid < 256) {
            if (j < a.jc + a.nsteps) {   // layer 0, step t = j
                const int t  = j;
                const int b0 = bid * 2, b1 = b0 + 1;
                const float* hp = h0buf + ((j + 1) & 1) * 131072;
                const float m0 = 1.f - (float)a.dones[t * 512 + b0];
                const float m1 = 1.f - (float)a.dones[t * 512 + b1];
                xs[0][tid] = hp[b0 * 256 + tid] * m0;
                xs[1][tid] = hp[b1 * 256 + tid] * m1;
                __syncthreads();
                const int u = tid;
                const size_t base0 = ((size_t)(j - a.jc) * 512 + b0) * 1024;
                const size_t base1 = ((size_t)(j - a.jc) * 512 + b1) * 1024;
                float ai0 = bf2f(a.xg0ck[base0 + u]),       af0 = bf2f(a.xg0ck[base0 + 256 + u]);
                float ag0 = bf2f(a.xg0ck[base0 + 512 + u]), ao0 = bf2f(a.xg0ck[base0 + 768 + u]);
                float ai1 = bf2f(a.xg0ck[base1 + u]),       af1 = bf2f(a.xg0ck[base1 + 256 + u]);
                float ag1 = bf2f(a.xg0ck[base1 + 512 + u]), ao1 = bf2f(a.xg0ck[base1 + 768 + u]);
                for (int k = 0; k < 256; k++) {
                    const uint_t pif = *(const uint_t*)(a.wt0 + (k << 10) + 2 * u);
                    const uint_t pgo = *(const uint_t*)(a.wt0 + (k << 10) + 512 + 2 * u);
                    const float wi = asf(pif << 16), wf = asf(pif & 0xFFFF0000u);
                    const float wg = asf(pgo << 16), wo = asf(pgo & 0xFFFF0000u);
                    const float h0v = xs[0][k], h1v = xs[1][k];
                    ai0 += h0v * wi; af0 += h0v * wf; ag0 += h0v * wg; ao0 += h0v * wo;
                    ai1 += h1v * wi; af1 += h1v * wf; ag1 += h1v * wg; ao1 += h1v * wo;
                }
                float* hc = h0buf + (j & 1) * 131072;
                {
                    const float cold = c0[b0 * 256 + u] * m0;
                    const float c2 = fsigm(af0) * cold + fsigm(ai0) * ftanh(ag0);
                    const float h2 = fsigm(ao0) * ftanh(c2);
                    c0[b0 * 256 + u] = c2; hc[b0 * 256 + u] = h2;
                }
                {
                    const float cold = c0[b1 * 256 + u] * m1;
                    const float c2 = fsigm(af1) * cold + fsigm(ai1) * ftanh(ag1);
                    const float h2 = fsigm(ao1) * ftanh(c2);
                    c0[b1 * 256 + u] = c2; hc[b1 * 256 + u] = h2;
                }
            }
        } else {
            if (j >= 1) {                // layer 1, step t = j-1
                const int t  = j - 1;
                const int bb = bid - 256;
                const int b0 = bb * 2, b1 = b0 + 1;
                const float* hl0 = h0buf + ((j - 1) & 1) * 131072;
                const float m0 = 1.f - (float)a.dones[t * 512 + b0];
                const float m1 = 1.f - (float)a.dones[t * 512 + b1];
                xs[0][tid]       = hl0[b0 * 256 + tid];
                xs[0][256 + tid] = h1[b0 * 256 + tid] * m0;
                xs[1][tid]       = hl0[b1 * 256 + tid];
                xs[1][256 + tid] = h1[b1 * 256 + tid] * m1;
                __syncthreads();
                const int u = tid;
                float ai0 = a.bias1[u], af0 = a.bias1[256 + u], ag0 = a.bias1[512 + u], ao0 = a.bias1[768 + u];
                float ai1 = ai0, af1 = af0, ag1 = ag0, ao1 = ao0;
                for (int k = 0; k < 512; k++) {
                    const uint_t pif = *(const uint_t*)(a.wt1 + (k << 10) + 2 * u);
                    const uint_t pgo = *(const uint_t*)(a.wt1 + (k << 10) + 512 + 2 * u);
                    const float wi = asf(pif << 16), wf = asf(pif & 0xFFFF0000u);
                    const float wg = asf(pgo << 16), wo = asf(pgo & 0xFFFF0000u);
                    const float h0v = xs[0][k], h1v = xs[1][k];
                    ai0 += h0v * wi; af0 += h0v * wf; ag0 += h0v * wg; ao0 += h0v * wo;
                    ai1 += h1v * wi; af1 += h1v * wf; ag1 += h1v * wg; ao1 += h1v * wo;
                }
                {
                    const float cold = c1[b0 * 256 + u] * m0;
                    const float c2 = fsigm(af0) * cold + fsigm(ai0) * ftanh(ag0);
                    const float h2 = fsigm(ao0) * ftanh(c2);
                    c1[b0 * 256 + u] = c2; h1[b0 * 256 + u] = h2;
                    a.outs[((size_t)t * 512 + b0) * 256 + u] = f2bf(h2);
                }
                {
                    const float cold = c1[b1 * 256 + u] * m1;
                    const float c2 = fsigm(af1) * cold + fsigm(ai1) * ftanh(ag1);
                    const float h2 = fsigm(ao1) * ftanh(c2);
                    c1[b1 * 256 + u] = c2; h1[b1 * 256 + u] = h2;
                    a.outs[((size_t)t * 512 + b1) * 256 + u] = f2bf(h2);
                }
            }
        }
        grid.sync();
    }
}

// ---------- forward loss + intrinsic reward (row-chunked), f32 out ----------
__global__ __launch_bounds__(256) void fl_k(const ushort_t* __restrict__ pn,
                                            const ushort_t* __restrict__ outs,
                                            float* __restrict__ out, float* __restrict__ acc,
                                            int r0, int out_size)
{
    __shared__ float bs[4];
    const int tid = threadIdx.x;
    const int w = tid >> 6, l = tid & 63;
    const size_t rl = (size_t)blockIdx.x * 4 + w;
    const size_t rg = rl + r0;
    const ushort_t* p = pn + rl * 256;
    const ushort_t* q = outs + (rg + 512) * 256;   // next_state_features = outs[t+1]
    float s = 0.f;
#pragma unroll
    for (int i = 0; i < 4; i++) {
        const float d = bf2f(p[l + i * 64]) - bf2f(q[l + i * 64]);
        s += d * d;
    }
#pragma unroll
    for (int off = 32; off > 0; off >>= 1) s += __shfl_down(s, off);
    if (l == 0) { if ((long long)(2 + rg) < out_size) out[2 + rg] = s; bs[w] = s; }
    __syncthreads();
    if (tid == 0) atomicAdd(acc, bs[0] + bs[1] + bs[2] + bs[3]);
}

// ---------- fused mu/std heads + inverse loss (row-chunked) ----------
__global__ __launch_bounds__(256) void musd_k(
    const ushort_t* __restrict__ mh, const ushort_t* __restrict__ sh,
    const float* __restrict__ Wm2, const float* __restrict__ bm2,
    const float* __restrict__ Ws2, const float* __restrict__ bs2,
    const float* __restrict__ action, float* __restrict__ acc, int r0)
{
    __shared__ __align__(16) ushort_t mhs[8][512];
    __shared__ __align__(16) ushort_t shs[8][512];
    __shared__ float red[256];
    const int tid = threadIdx.x;
    const size_t rl0 = (size_t)blockIdx.x * 8;
    for (int i = tid; i < 512; i += 256) {
        const int row = i >> 6, c = (i & 63) * 8;
        *(uint4*)&mhs[row][c] = *(const uint4*)&mh[(rl0 + row) * 512 + c];
        *(uint4*)&shs[row][c] = *(const uint4*)&sh[(rl0 + row) * 512 + c];
    }
    __syncthreads();
    const int row = tid >> 5, c = tid & 31;
    float am = bm2[c], asv = bs2[c];
    for (int k = 0; k < 512; k += 8) {
        const float4 wa = *(const float4*)&Wm2[c * 512 + k];
        const float4 wb = *(const float4*)&Wm2[c * 512 + k + 4];
        const float4 sa = *(const float4*)&Ws2[c * 512 + k];
        const float4 sb = *(const float4*)&Ws2[c * 512 + k + 4];
        const float* wp = (const float*)&wa;   // wa,wb contiguous? no — index separately
        am  += bf2f(mhs[row][k + 0]) * wa.x + bf2f(mhs[row][k + 1]) * wa.y
             + bf2f(mhs[row][k + 2]) * wa.z + bf2f(mhs[row][k + 3]) * wa.w
             + bf2f(mhs[row][k + 4]) * wb.x + bf2f(mhs[row][k + 5]) * wb.y
             + bf2f(mhs[row][k + 6]) * wb.z + bf2f(mhs[row][k + 7]) * wb.w;
        asv += bf2f(shs[row][k + 0]) * sa.x + bf2f(shs[row][k + 1]) * sa.y
             + bf2f(shs[row][k + 2]) * sa.z + bf2f(shs[row][k + 3]) * sa.w
             + bf2f(shs[row][k + 4]) * sb.x + bf2f(shs[row][k + 5]) * sb.y
             + bf2f(shs[row][k + 6]) * sb.z + bf2f(shs[row][k + 7]) * sb.w;
        (void)wp;
    }
    const float mu = ftanh(am);
    const float sp = fmaxf(asv, 0.f) + log1pf(__expf(-fabsf(asv)));   // softplus
    const float a  = action[(rl0 + r0 + row) * 32 + c];
    const float z  = (a - mu) / sp;
    red[tid] = 0.5f * z * z + __logf(sp) + 0.918938533204672741f;     // -log_prob
    __syncthreads();
    for (int s = 128; s > 0; s >>= 1) { if (tid < s) red[tid] += red[tid + s]; __syncthreads(); }
    if (tid == 0) atomicAdd(acc, red[0]);
}

// ---------- finalize: scalar losses + hidden copy-out (f32) ----------
__global__ __launch_bounds__(256) void fin_k(const float* __restrict__ acc,
                                             const float* __restrict__ st,
                                             float* __restrict__ out, int out_size)
{
    const size_t idx = (size_t)blockIdx.x * 256 + threadIdx.x;
    if (idx == 0 && out_size > 0) out[0] = acc[0] / 33554432.f;   // mean over 256*512*256
    if (idx == 1 && out_size > 1) out[1] = acc[1] / 4194304.f;    // mean over 256*512*32
    if (idx < 524288) {
        const int which = (int)(idx >> 17);
        const float* src;
        if      (which == 0) src = st;             // h_l0 final (tick 256 -> parity 0)
        else if (which == 1) src = st + 393216;    // h_l1
        else if (which == 2) src = st + 262144;    // c_l0
        else                 src = st + 524288;    // c_l1
        const size_t o = 2 + 131072 + idx;
        if ((long long)o < out_size) out[o] = src[idx & 131071];
    }
}

extern "C" void kernel_launch(void* const* d_in, const int* in_sizes, int n_in,
                              void* d_out, int out_size, void* d_ws, size_t ws_size,
                              hipStream_t stream)
{
    const float* states = (const float*)d_in[0];
    const float* action = (const float*)d_in[1];
    const int*   dones  = (const int*)d_in[2];
    const float* Wfe  = (const float*)d_in[3];
    const float* bfe  = (const float*)d_in[4];
    const float* Wih0 = (const float*)d_in[5];
    const float* Whh0 = (const float*)d_in[6];
    const float* bih0 = (const float*)d_in[7];
    const float* bhh0 = (const float*)d_in[8];
    const float* Wih1 = (const float*)d_in[9];
    const float* Whh1 = (const float*)d_in[10];
    const float* bih1 = (const float*)d_in[11];
    const float* bhh1 = (const float*)d_in[12];
    const float* Wf1  = (const float*)d_in[13];
    const float* bf1  = (const float*)d_in[14];
    const float* Wf2  = (const float*)d_in[15];
    const float* bf2  = (const float*)d_in[16];
    const float* Wm1  = (const float*)d_in[17];
    const float* bm1  = (const float*)d_in[18];
    const float* Wm2  = (const float*)d_in[19];
    const float* bm2  = (const float*)d_in[20];
    const float* Ws1  = (const float*)d_in[21];
    const float* bs1  = (const float*)d_in[22];
    const float* Ws2  = (const float*)d_in[23];
    const float* bs2  = (const float*)d_in[24];

    // ---------- adaptive workspace layout ----------
    char* ws = (char*)d_ws;
    const size_t OUTS_B = 67371008;   // 257*512*256*2 (bf16)
    const size_t ST_B   = 2621440;    // 5*131072*4
    const size_t WT0_B  = 524288;
    const size_t WT1_B  = 1048576;
    const size_t BIAS_B = 4096;
    const size_t ACC_B  = 256;

    size_t off = 0;
    ushort_t* outs  = (ushort_t*)(ws + off); off += OUTS_B;
    float*    st    = (float*)(ws + off);    off += ST_B;
    ushort_t* wt0   = (ushort_t*)(ws + off); off += WT0_B;
    ushort_t* wt1   = (ushort_t*)(ws + off); off += WT1_B;
    float*    bias1 = (float*)(ws + off);    off += BIAS_B;
    float*    accp  = (float*)(ws + off);    off += ACC_B;
    char*     S     = ws + off;               // shared scratch for both phases
    const size_t avail = (ws_size > off) ? (ws_size - off) : 0;

    // scan-phase chunk: per step feats bf16 (524288 B) + xg0 bf16 (1048576 B)
    int TC = (int)(avail / 1572864);
    if (TC > 257) TC = 257;
    if (TC < 1)   TC = 1;
    // head-phase chunk: per row ph(1024)+pn(512)+mh(1024)+sh(1024) bytes (bf16)
    long long rc = (long long)(avail / 3584) & ~63LL;
    if (rc > 131072) rc = 131072;
    if (rc < 64)     rc = 64;
    const int RC = (int)rc;

    hipMemsetAsync(accp, 0, ACC_B, stream);

    prep_k<<<512, 256, 0, stream>>>(Whh0, Wih1, Whh1, bih1, bhh1, wt0, wt1, bias1);

    // ---------- scan phase (time-chunked) ----------
    ushort_t* featsck = (ushort_t*)S;
    ushort_t* xg0ck   = (ushort_t*)(S + (size_t)TC * 524288);
    for (int jc = 0; jc < 257; jc += TC) {
        const int nsteps = (257 - jc < TC) ? (257 - jc) : TC;
        const int jend   = (jc + TC < 257) ? (jc + TC) : 258;   // last chunk drains tick 257
        // feats = relu(states_chunk @ Wfe^T + bfe)   [A: f32, out: bf16]
        gemm_k<0, 1, 1, float, float><<<dim3(nsteps * 8, 8), 256, 0, stream>>>(
            states + (size_t)jc * 512 * 128, nullptr, Wfe, bfe, nullptr, featsck, 128, 512);
        // xg0 = feats @ Wih0^T + bih0 + bhh0         [A: bf16, out: bf16]
        gemm_k<0, 0, 2, ushort_t, ushort_t><<<dim3(nsteps * 8, 16), 256, 0, stream>>>(
            featsck, nullptr, Wih0, bih0, bhh0, xg0ck, 512, 1024);
        // pipelined cooperative scan for ticks [jc, jend)
        RecArgs ra{ xg0ck, dones, wt0, wt1, bias1, st, outs, jc, jend, nsteps, (jc == 0) ? 1 : 0 };
        void* kargs[] = { &ra };
        hipLaunchCooperativeKernel(rec_k, dim3(512), dim3(256), kargs, 0, stream);
    }

    // ---------- head phase (row-chunked) ----------
    for (int r0 = 0; r0 < M_SEQ; r0 += RC) {
        const int rows = (M_SEQ - r0 < RC) ? (M_SEQ - r0) : RC;
        ushort_t* ph = (ushort_t*)S;
        ushort_t* pn = (ushort_t*)(S + (size_t)rows * 1024);
        ushort_t* mh = (ushort_t*)(S + (size_t)rows * 1536);
        ushort_t* sh = (ushort_t*)(S + (size_t)rows * 2560);
        // pred_hidden = relu([sf, action] @ Wf1^T + bf1)   [A1 bf16, A2 f32]
        gemm_k<1, 1, 1, ushort_t, float><<<dim3(rows / 64, 8), 256, 0, stream>>>(
            outs + (size_t)r0 * 256, action + (size_t)r0 * 32, Wf1, bf1, nullptr, ph, 288, 512);
        // pred_next = pred_hidden @ Wf2^T + bf2            [A bf16]
        gemm_k<0, 0, 1, ushort_t, ushort_t><<<dim3(rows / 64, 4), 256, 0, stream>>>(
            ph, nullptr, Wf2, bf2, nullptr, pn, 512, 256);
        // forward loss + intrinsic reward
        fl_k<<<rows / 4, 256, 0, stream>>>(pn, outs, (float*)d_out, accp, r0, out_size);
        // mh / sh = relu([sf, pred_next] @ W^T + b)        [A1 bf16, A2 bf16]
        gemm_k<2, 1, 1, ushort_t, ushort_t><<<dim3(rows / 64, 8), 256, 0, stream>>>(
            outs + (size_t)r0 * 256, pn, Wm1, bm1, nullptr, mh, 512, 512);
        gemm_k<2, 1, 1, ushort_t, ushort_t><<<dim3(rows / 64, 8), 256, 0, stream>>>(
            outs + (size_t)r0 * 256, pn, Ws1, bs1, nullptr, sh, 512, 512);
        // mu/std heads + inverse loss
        musd_k<<<rows / 8, 256, 0, stream>>>(mh, sh, Wm2, bm2, Ws2, bs2, action, accp + 1, r0);
    }

    // scalars + hidden
    fin_k<<<2048, 256, 0, stream>>>(accp, st, (float*)d_out, out_size);
}

// Round 7
// 24584.454 us; speedup vs baseline: 1.0500x; 1.0500x over previous
//
#include <hip/hip_runtime.h>
#include <hip/hip_bf16.h>
#include <hip/hip_cooperative_groups.h>

namespace cg = cooperative_groups;

typedef unsigned short ushort_t;
typedef unsigned int   uint_t;

// Problem constants: T1=257, B=512, SD=128, AD=32, HS=512, SF=256, L=2
#define M_ALL 131584   // 257*512
#define M_SEQ 131072   // 256*512

// ---------- helpers ----------
__device__ __forceinline__ float bf2f(ushort_t u) {
    union { uint_t i; float f; } v; v.i = ((uint_t)u) << 16; return v.f;
}
__device__ __forceinline__ float asf(uint_t i) {
    union { uint_t u; float f; } v; v.u = i; return v.f;
}
__device__ __forceinline__ ushort_t f2bf(float f) {
    union { float f; uint_t i; } v; v.f = f;
    uint_t r = v.i + 0x7FFFu + ((v.i >> 16) & 1u);
    return (ushort_t)(r >> 16);
}
__device__ __forceinline__ float fsigm(float x) { return 1.f / (1.f + __expf(-x)); }
__device__ __forceinline__ float ftanh(float x) {
    x = fminf(15.f, fmaxf(-15.f, x));
    float e = __expf(2.f * x);
    return (e - 1.f) / (e + 1.f);
}

typedef __attribute__((ext_vector_type(8))) short  bfrag;   // 8 x bf16
typedef __attribute__((ext_vector_type(4))) float  ffrag;   // 4 x f32 accum

// stage 8 elements into LDS as bf16 (f32 source converts, bf16 source copies)
__device__ __forceinline__ void stage8(const float* p, ushort_t* dst) {
    const float4 a = *(const float4*)p;
    const float4 b = *(const float4*)(p + 4);
    bfrag v;
    v[0] = (short)f2bf(a.x); v[1] = (short)f2bf(a.y);
    v[2] = (short)f2bf(a.z); v[3] = (short)f2bf(a.w);
    v[4] = (short)f2bf(b.x); v[5] = (short)f2bf(b.y);
    v[6] = (short)f2bf(b.z); v[7] = (short)f2bf(b.w);
    *(bfrag*)dst = v;
}
__device__ __forceinline__ void stage8(const ushort_t* p, ushort_t* dst) {
    *(uint4*)dst = *(const uint4*)p;
}

// ---------- generic bf16 MFMA GEMM: C = act(A @ W^T + bias), C bf16, W bf16, bias f32 ----------
// AMODE 0: plain A1 (stride K)
// AMODE 1: k<256 -> A1 stride 256 ; k>=256 -> A2 stride 32  (x = [sf, action])
// AMODE 2: k<256 -> A1 stride 256 ; k>=256 -> A2 stride 256 (xi = [sf, pred_next])
template<int AMODE, int ACT, typename TA1, typename TA2>
__global__ __launch_bounds__(256) void gemm_k(
    const TA1* __restrict__ A1, const TA2* __restrict__ A2,
    const ushort_t* __restrict__ W, const float* __restrict__ b1,
    ushort_t* __restrict__ C, int K, int N)
{
    __shared__ __align__(16) ushort_t As[64][40];
    __shared__ __align__(16) ushort_t Ws[64][40];

    const int tid  = threadIdx.x;
    const int m0   = blockIdx.x * 64;
    const int n0   = blockIdx.y * 64;
    const int lane = tid & 63;
    const int wv   = tid >> 6;
    const int wm   = (wv & 1) * 32;
    const int wn   = (wv >> 1) * 32;
    const int quad = lane >> 4;
    const int ln   = lane & 15;

    ffrag acc[2][2];
#pragma unroll
    for (int i = 0; i < 2; i++)
#pragma unroll
        for (int j = 0; j < 2; j++) acc[i][j] = (ffrag){0.f, 0.f, 0.f, 0.f};

    const int arow = tid >> 2;        // 0..63
    const int acol = (tid & 3) * 8;   // 0,8,16,24

    for (int k0 = 0; k0 < K; k0 += 32) {
        const int kk = k0 + acol;
        if (AMODE == 0) {
            stage8(A1 + (size_t)(m0 + arow) * K + kk, &As[arow][acol]);
        } else if (AMODE == 1) {
            if (kk < 256) stage8(A1 + (size_t)(m0 + arow) * 256 + kk, &As[arow][acol]);
            else          stage8(A2 + (size_t)(m0 + arow) * 32 + (kk - 256), &As[arow][acol]);
        } else {
            if (kk < 256) stage8(A1 + (size_t)(m0 + arow) * 256 + kk, &As[arow][acol]);
            else          stage8(A2 + (size_t)(m0 + arow) * 256 + (kk - 256), &As[arow][acol]);
        }
        stage8(W + (size_t)(n0 + arow) * K + kk, &Ws[arow][acol]);
        __syncthreads();

        bfrag af[2], bfv[2];
#pragma unroll
        for (int i = 0; i < 2; i++) af[i]  = *(const bfrag*)&As[wm + i * 16 + ln][quad * 8];
#pragma unroll
        for (int j = 0; j < 2; j++) bfv[j] = *(const bfrag*)&Ws[wn + j * 16 + ln][quad * 8];
#pragma unroll
        for (int i = 0; i < 2; i++)
#pragma unroll
            for (int j = 0; j < 2; j++)
                acc[i][j] = __builtin_amdgcn_mfma_f32_16x16x32_bf16(af[i], bfv[j], acc[i][j], 0, 0, 0);
        __syncthreads();
    }

#pragma unroll
    for (int j = 0; j < 2; j++) {
        const int n = n0 + wn + j * 16 + ln;
        const float bias = b1[n];
#pragma unroll
        for (int i = 0; i < 2; i++) {
#pragma unroll
            for (int r = 0; r < 4; r++) {
                const int m = m0 + wm + i * 16 + quad * 4 + r;
                float x = acc[i][j][r] + bias;
                if (ACT == 1) x = fmaxf(x, 0.f);
                C[(size_t)m * N + n] = f2bf(x);
            }
        }
    }
}

// ---------- prep: bf16 weights + R3's gate-interleaved recurrent layouts ----------
// wt0[k*1024 + 2u+{0,1}] = Whh0[{i,f}-gate row u][k]; wt0[k*1024+512+2u+{0,1}] = {g,o}.
struct PrepArgs {
    const float *Wfe, *Wih0, *Whh0, *bih0, *bhh0, *Wih1, *Whh1, *bih1, *bhh1;
    const float *Wf1, *Wf2, *Wm1, *Ws1, *Wm2, *Ws2;
    ushort_t *Wfe_b, *Wih0_b, *wt0, *wt1, *Wf1_b, *Wf2_b, *Wm1_b, *Ws1_b;
    float *W2t, *bias0s, *bias1s;
};
__global__ __launch_bounds__(256) void prep_k(PrepArgs a)
{
    const int idx = blockIdx.x * 256 + threadIdx.x;
    const int stride = gridDim.x * 256;
    for (int e = idx; e < 65536; e += stride)  a.Wfe_b[e]  = f2bf(a.Wfe[e]);
    for (int e = idx; e < 524288; e += stride) a.Wih0_b[e] = f2bf(a.Wih0[e]);   // original order
    for (int e = idx; e < 262144; e += stride) {              // wt0 (R3-exact)
        const int k = e >> 10, q = e & 1023;
        const int s = q & 1, u = (q >> 1) & 255;
        const int j = ((q >> 9) << 9) + s * 256 + u;
        a.wt0[e] = f2bf(a.Whh0[j * 256 + k]);
    }
    for (int e = idx; e < 524288; e += stride) {              // wt1 (R3-exact)
        const int k = e >> 10, q = e & 1023;
        const int s = q & 1, u = (q >> 1) & 255;
        const int j = ((q >> 9) << 9) + s * 256 + u;
        a.wt1[e] = f2bf((k < 256) ? a.Wih1[j * 256 + k] : a.Whh1[j * 256 + (k - 256)]);
    }
    for (int e = idx; e < 147456; e += stride) a.Wf1_b[e] = f2bf(a.Wf1[e]);
    for (int e = idx; e < 131072; e += stride) a.Wf2_b[e] = f2bf(a.Wf2[e]);
    for (int e = idx; e < 262144; e += stride) a.Wm1_b[e] = f2bf(a.Wm1[e]);
    for (int e = idx; e < 262144; e += stride) a.Ws1_b[e] = f2bf(a.Ws1[e]);
    for (int e = idx; e < 32768; e += stride) {               // W2t: (512,64) k-major f32
        const int k = e >> 6, c = e & 63;
        a.W2t[e] = (c < 32) ? a.Wm2[c * 512 + k] : a.Ws2[(c - 32) * 512 + k];
    }
    for (int e = idx; e < 1024; e += stride) {
        a.bias0s[e] = a.bih0[e] + a.bhh0[e];
        a.bias1s[e] = a.bih1[e] + a.bhh1[e];
    }
}

// ---------- persistent cooperative LSTM scan (R3-proven numerics, MLP-batched loads) ----------
struct Rec3Args {
    const ushort_t* xg0;     // chunk: (nsteps*512, 1024) bf16, ORIGINAL gate order, biases included
    const int*      dones;   // (257,512) int32
    const ushort_t* wt0;     // interleaved Whh0 (256,1024) bf16
    const ushort_t* wt1;     // interleaved [Wih1;Whh1] (512,1024) bf16
    const float*    bias1s;  // (1024) original order
    float*          st;      // h0buf[2] | c0 | h1 | c1 : 5*131072+131072 = 655360 f32
    ushort_t*       outs;    // (257*512, 256) bf16
    int jc, jend, nsteps, init;
};

__global__ __launch_bounds__(256, 2) void rec3_k(Rec3Args a)
{
    cg::grid_group grid = cg::this_grid();
    __shared__ __align__(16) float xs[2][512];
    const int tid = threadIdx.x;
    const int bid = blockIdx.x;

    float* h0buf = a.st;
    float* c0    = a.st + 262144;
    float* h1    = a.st + 393216;
    float* c1    = a.st + 524288;

    if (a.init) {
        const int idx = bid * 256 + tid;
#pragma unroll
        for (int i = 0; i < 5; i++) a.st[idx + i * 131072] = 0.f;
        grid.sync();
    }

    const int u = tid;
    for (int j = a.jc; j < a.jend; ++j) {
        if (bid < 256) {
            if (j < a.jc + a.nsteps) {   // ---- layer 0, step t = j ----
                const int t  = j;
                const int b0 = bid * 2, b1 = b0 + 1;
                const float* hp = h0buf + ((size_t)((j + 1) & 1)) * 131072;
                const float m0 = 1.f - (float)a.dones[t * 512 + b0];
                const float m1 = 1.f - (float)a.dones[t * 512 + b1];
                xs[0][tid] = hp[b0 * 256 + tid] * m0;
                xs[1][tid] = hp[b1 * 256 + tid] * m1;
                __syncthreads();
                const size_t base0 = ((size_t)(t - a.jc) * 512 + b0) * 1024;
                const size_t base1 = ((size_t)(t - a.jc) * 512 + b1) * 1024;
                float ai0 = bf2f(a.xg0[base0 + u]),       af0 = bf2f(a.xg0[base0 + 256 + u]);
                float ag0 = bf2f(a.xg0[base0 + 512 + u]), ao0 = bf2f(a.xg0[base0 + 768 + u]);
                float ai1 = bf2f(a.xg0[base1 + u]),       af1 = bf2f(a.xg0[base1 + 256 + u]);
                float ag1 = bf2f(a.xg0[base1 + 512 + u]), ao1 = bf2f(a.xg0[base1 + 768 + u]);
                for (int k0 = 0; k0 < 256; k0 += 8) {
                    uint_t pif[8], pgo[8];
#pragma unroll
                    for (int e = 0; e < 8; e++) {
                        pif[e] = *(const uint_t*)(a.wt0 + ((k0 + e) << 10) + 2 * u);
                        pgo[e] = *(const uint_t*)(a.wt0 + ((k0 + e) << 10) + 512 + 2 * u);
                    }
                    float h0r[8], h1r[8];
                    *(float4*)&h0r[0] = *(const float4*)&xs[0][k0];
                    *(float4*)&h0r[4] = *(const float4*)&xs[0][k0 + 4];
                    *(float4*)&h1r[0] = *(const float4*)&xs[1][k0];
                    *(float4*)&h1r[4] = *(const float4*)&xs[1][k0 + 4];
#pragma unroll
                    for (int e = 0; e < 8; e++) {
                        const float wi = asf(pif[e] << 16), wf = asf(pif[e] & 0xFFFF0000u);
                        const float wg = asf(pgo[e] << 16), wo = asf(pgo[e] & 0xFFFF0000u);
                        ai0 += h0r[e] * wi; af0 += h0r[e] * wf; ag0 += h0r[e] * wg; ao0 += h0r[e] * wo;
                        ai1 += h1r[e] * wi; af1 += h1r[e] * wf; ag1 += h1r[e] * wg; ao1 += h1r[e] * wo;
                    }
                }
                float* hc = h0buf + ((size_t)(j & 1)) * 131072;
                {
                    const float cold = c0[b0 * 256 + u] * m0;
                    const float c2 = fsigm(af0) * cold + fsigm(ai0) * ftanh(ag0);
                    const float h2 = fsigm(ao0) * ftanh(c2);
                    c0[b0 * 256 + u] = c2; hc[b0 * 256 + u] = h2;
                }
                {
                    const float cold = c0[b1 * 256 + u] * m1;
                    const float c2 = fsigm(af1) * cold + fsigm(ai1) * ftanh(ag1);
                    const float h2 = fsigm(ao1) * ftanh(c2);
                    c0[b1 * 256 + u] = c2; hc[b1 * 256 + u] = h2;
                }
            }
        } else {
            if (j >= 1) {                // ---- layer 1, step t = j-1 ----
                const int t  = j - 1;
                const int bb = bid - 256;
                const int b0 = bb * 2, b1 = b0 + 1;
                const float* hl0 = h0buf + ((size_t)((j - 1) & 1)) * 131072;
                const float m0 = 1.f - (float)a.dones[t * 512 + b0];
                const float m1 = 1.f - (float)a.dones[t * 512 + b1];
                xs[0][tid]       = hl0[b0 * 256 + tid];
                xs[0][256 + tid] = h1[b0 * 256 + tid] * m0;
                xs[1][tid]       = hl0[b1 * 256 + tid];
                xs[1][256 + tid] = h1[b1 * 256 + tid] * m1;
                __syncthreads();
                float ai0 = a.bias1s[u], af0 = a.bias1s[256 + u];
                float ag0 = a.bias1s[512 + u], ao0 = a.bias1s[768 + u];
                float ai1 = ai0, af1 = af0, ag1 = ag0, ao1 = ao0;
                for (int k0 = 0; k0 < 512; k0 += 8) {
                    uint_t pif[8], pgo[8];
#pragma unroll
                    for (int e = 0; e < 8; e++) {
                        pif[e] = *(const uint_t*)(a.wt1 + ((k0 + e) << 10) + 2 * u);
                        pgo[e] = *(const uint_t*)(a.wt1 + ((k0 + e) << 10) + 512 + 2 * u);
                    }
                    float h0r[8], h1r[8];
                    *(float4*)&h0r[0] = *(const float4*)&xs[0][k0];
                    *(float4*)&h0r[4] = *(const float4*)&xs[0][k0 + 4];
                    *(float4*)&h1r[0] = *(const float4*)&xs[1][k0];
                    *(float4*)&h1r[4] = *(const float4*)&xs[1][k0 + 4];
#pragma unroll
                    for (int e = 0; e < 8; e++) {
                        const float wi = asf(pif[e] << 16), wf = asf(pif[e] & 0xFFFF0000u);
                        const float wg = asf(pgo[e] << 16), wo = asf(pgo[e] & 0xFFFF0000u);
                        ai0 += h0r[e] * wi; af0 += h0r[e] * wf; ag0 += h0r[e] * wg; ao0 += h0r[e] * wo;
                        ai1 += h1r[e] * wi; af1 += h1r[e] * wf; ag1 += h1r[e] * wg; ao1 += h1r[e] * wo;
                    }
                }
                {
                    const float cold = c1[b0 * 256 + u] * m0;
                    const float c2 = fsigm(af0) * cold + fsigm(ai0) * ftanh(ag0);
                    const float h2 = fsigm(ao0) * ftanh(c2);
                    c1[b0 * 256 + u] = c2; h1[b0 * 256 + u] = h2;
                    a.outs[((size_t)t * 512 + b0) * 256 + u] = f2bf(h2);
                }
                {
                    const float cold = c1[b1 * 256 + u] * m1;
                    const float c2 = fsigm(af1) * cold + fsigm(ai1) * ftanh(ag1);
                    const float h2 = fsigm(ao1) * ftanh(c2);
                    c1[b1 * 256 + u] = c2; h1[b1 * 256 + u] = h2;
                    a.outs[((size_t)t * 512 + b1) * 256 + u] = f2bf(h2);
                }
            }
        }
        grid.sync();
    }
}

// ---------- forward loss + intrinsic reward (row-chunked), f32 out ----------
__global__ __launch_bounds__(256) void fl_k(const ushort_t* __restrict__ pn,
                                            const ushort_t* __restrict__ outs,
                                            float* __restrict__ out, float* __restrict__ acc,
                                            int r0, int out_size)
{
    __shared__ float bs[4];
    const int tid = threadIdx.x;
    const int w = tid >> 6, l = tid & 63;
    const size_t rl = (size_t)blockIdx.x * 4 + w;
    const size_t rg = rl + r0;
    const ushort_t* p = pn + rl * 256;
    const ushort_t* q = outs + (rg + 512) * 256;   // next_state_features = outs[t+1]
    float s = 0.f;
#pragma unroll
    for (int i = 0; i < 4; i++) {
        const float d = bf2f(p[l + i * 64]) - bf2f(q[l + i * 64]);
        s += d * d;
    }
#pragma unroll
    for (int off = 32; off > 0; off >>= 1) s += __shfl_down(s, off);
    if (l == 0) { if ((long long)(2 + rg) < out_size) out[2 + rg] = s; bs[w] = s; }
    __syncthreads();
    if (tid == 0) atomicAdd(acc, bs[0] + bs[1] + bs[2] + bs[3]);
}

// ---------- fused mu/std heads + inverse loss (row-chunked), coalesced W2t ----------
__global__ __launch_bounds__(256) void musd_k(
    const ushort_t* __restrict__ mh, const ushort_t* __restrict__ sh,
    const float* __restrict__ W2t, const float* __restrict__ bm2,
    const float* __restrict__ bs2, const float* __restrict__ action,
    float* __restrict__ acc, int r0)
{
    __shared__ __align__(16) ushort_t mhs[8][512];
    __shared__ __align__(16) ushort_t shs[8][512];
    __shared__ float red[256];
    const int tid = threadIdx.x;
    const size_t rl0 = (size_t)blockIdx.x * 8;
    for (int i = tid; i < 512; i += 256) {
        const int row = i >> 6, c = (i & 63) * 8;
        *(uint4*)&mhs[row][c] = *(const uint4*)&mh[(rl0 + row) * 512 + c];
        *(uint4*)&shs[row][c] = *(const uint4*)&sh[(rl0 + row) * 512 + c];
    }
    __syncthreads();
    const int row = tid >> 5, c = tid & 31;
    float am = bm2[c], asv = bs2[c];
    for (int k = 0; k < 512; k += 8) {
#pragma unroll
        for (int e = 0; e < 8; e++) {
            const float wm = W2t[(k + e) * 64 + c];
            const float wsv = W2t[(k + e) * 64 + 32 + c];
            am  += bf2f(mhs[row][k + e]) * wm;
            asv += bf2f(shs[row][k + e]) * wsv;
        }
    }
    const float mu = ftanh(am);
    const float sp = fmaxf(asv, 0.f) + log1pf(__expf(-fabsf(asv)));   // softplus
    const float a  = action[(rl0 + r0 + row) * 32 + c];
    const float z  = (a - mu) / sp;
    red[tid] = 0.5f * z * z + __logf(sp) + 0.918938533204672741f;     // -log_prob
    __syncthreads();
    for (int s = 128; s > 0; s >>= 1) { if (tid < s) red[tid] += red[tid + s]; __syncthreads(); }
    if (tid == 0) atomicAdd(acc, red[0]);
}

// ---------- finalize: scalar losses + hidden copy-out (f32), R3-proven mapping ----------
__global__ __launch_bounds__(256) void fin_k(const float* __restrict__ acc,
                                             const float* __restrict__ st,
                                             float* __restrict__ out, int out_size)
{
    const size_t idx = (size_t)blockIdx.x * 256 + threadIdx.x;
    if (idx == 0 && out_size > 0) out[0] = acc[0] / 33554432.f;   // mean over 256*512*256
    if (idx == 1 && out_size > 1) out[1] = acc[1] / 4194304.f;    // mean over 256*512*32
    if (idx < 524288) {
        const int which = (int)(idx >> 17);
        const float* src;
        if      (which == 0) src = st;             // h_l0 final (t=256, parity 0)
        else if (which == 1) src = st + 393216;    // h_l1 final
        else if (which == 2) src = st + 262144;    // c_l0
        else                 src = st + 524288;    // c_l1
        const size_t o = 2 + 131072 + idx;
        if ((long long)o < out_size) out[o] = src[idx & 131071];
    }
}

extern "C" void kernel_launch(void* const* d_in, const int* in_sizes, int n_in,
                              void* d_out, int out_size, void* d_ws, size_t ws_size,
                              hipStream_t stream)
{
    const float* states = (const float*)d_in[0];
    const float* action = (const float*)d_in[1];
    const int*   dones  = (const int*)d_in[2];
    const float* Wfe  = (const float*)d_in[3];
    const float* bfe  = (const float*)d_in[4];
    const float* Wih0 = (const float*)d_in[5];
    const float* Whh0 = (const float*)d_in[6];
    const float* bih0 = (const float*)d_in[7];
    const float* bhh0 = (const float*)d_in[8];
    const float* Wih1 = (const float*)d_in[9];
    const float* Whh1 = (const float*)d_in[10];
    const float* bih1 = (const float*)d_in[11];
    const float* bhh1 = (const float*)d_in[12];
    const float* Wf1  = (const float*)d_in[13];
    const float* bf1  = (const float*)d_in[14];
    const float* Wf2  = (const float*)d_in[15];
    const float* bf2  = (const float*)d_in[16];
    const float* Wm1  = (const float*)d_in[17];
    const float* bm1  = (const float*)d_in[18];
    const float* Wm2  = (const float*)d_in[19];
    const float* bm2  = (const float*)d_in[20];
    const float* Ws1  = (const float*)d_in[21];
    const float* bs1  = (const float*)d_in[22];
    const float* Ws2  = (const float*)d_in[23];
    const float* bs2  = (const float*)d_in[24];

    // ---------- workspace layout (persistent region) ----------
    char* ws = (char*)d_ws;
    size_t off = 0;
    ushort_t* outs    = (ushort_t*)(ws + off); off += 67371008;  // 257*512*256 bf16
    float*    st      = (float*)(ws + off);    off += 2621440;   // 655360 f32
    ushort_t* wt0     = (ushort_t*)(ws + off); off += 524288;
    ushort_t* wt1     = (ushort_t*)(ws + off); off += 1048576;
    ushort_t* Wfe_b   = (ushort_t*)(ws + off); off += 131072;
    ushort_t* Wih0_b  = (ushort_t*)(ws + off); off += 1048576;
    ushort_t* Wf1_b   = (ushort_t*)(ws + off); off += 294912;
    ushort_t* Wf2_b   = (ushort_t*)(ws + off); off += 262144;
    ushort_t* Wm1_b   = (ushort_t*)(ws + off); off += 524288;
    ushort_t* Ws1_b   = (ushort_t*)(ws + off); off += 524288;
    float*    W2t     = (float*)(ws + off);    off += 131072;
    float*    bias0s  = (float*)(ws + off);    off += 4096;
    float*    bias1s  = (float*)(ws + off);    off += 4096;
    float*    accp    = (float*)(ws + off);    off += 256;
    char*     S       = ws + off;              // chunk scratch
    const size_t avail = (ws_size > off) ? (ws_size - off) : 0;

    // scan-phase chunk: per step feats bf16 (524288 B) + xg0 bf16 (1048576 B)
    int TC = (int)(avail / 1572864);
    if (TC > 257) TC = 257;
    if (TC < 1)   TC = 1;
    // head-phase chunk: per row ph(1024)+pn(512)+mh(1024)+sh(1024) bytes (bf16)
    long long rc = (long long)(avail / 3584) & ~63LL;
    if (rc > 131072) rc = 131072;
    if (rc < 64)     rc = 64;
    const int RC = (int)rc;

    hipMemsetAsync(accp, 0, 256, stream);

    PrepArgs pa{ Wfe, Wih0, Whh0, bih0, bhh0, Wih1, Whh1, bih1, bhh1,
                 Wf1, Wf2, Wm1, Ws1, Wm2, Ws2,
                 Wfe_b, Wih0_b, wt0, wt1, Wf1_b, Wf2_b, Wm1_b, Ws1_b,
                 W2t, bias0s, bias1s };
    prep_k<<<512, 256, 0, stream>>>(pa);

    // ---------- scan phase (time-chunked) ----------
    ushort_t* featsck = (ushort_t*)S;
    ushort_t* xg0ck   = (ushort_t*)(S + (size_t)TC * 524288);
    for (int jc = 0; jc < 257; jc += TC) {
        const int nsteps = (257 - jc < TC) ? (257 - jc) : TC;
        const int jend   = (jc + TC < 257) ? (jc + TC) : 258;   // last chunk drains tick 257
        // feats = relu(states_chunk @ Wfe^T + bfe)
        gemm_k<0, 1, float, float><<<dim3(nsteps * 8, 8), 256, 0, stream>>>(
            states + (size_t)jc * 512 * 128, nullptr, Wfe_b, bfe, featsck, 128, 512);
        // xg0 = feats @ Wih0^T + (bih0 + bhh0), ORIGINAL column order
        gemm_k<0, 0, ushort_t, ushort_t><<<dim3(nsteps * 8, 16), 256, 0, stream>>>(
            featsck, nullptr, Wih0_b, bias0s, xg0ck, 512, 1024);
        // pipelined cooperative scan for ticks [jc, jend)
        Rec3Args ra{ xg0ck, dones, wt0, wt1, bias1s, st, outs,
                     jc, jend, nsteps, (jc == 0) ? 1 : 0 };
        void* kargs[] = { &ra };
        hipLaunchCooperativeKernel(rec3_k, dim3(512), dim3(256), kargs, 0, stream);
    }

    // ---------- head phase (row-chunked) ----------
    for (int r0 = 0; r0 < M_SEQ; r0 += RC) {
        const int rows = (M_SEQ - r0 < RC) ? (M_SEQ - r0) : RC;
        ushort_t* ph = (ushort_t*)S;
        ushort_t* pn = (ushort_t*)(S + (size_t)rows * 1024);
        ushort_t* mh = (ushort_t*)(S + (size_t)rows * 1536);
        ushort_t* sh = (ushort_t*)(S + (size_t)rows * 2560);
        // pred_hidden = relu([sf, action] @ Wf1^T + bf1)
        gemm_k<1, 1, ushort_t, float><<<dim3(rows / 64, 8), 256, 0, stream>>>(
            outs + (size_t)r0 * 256, action + (size_t)r0 * 32, Wf1_b, bf1, ph, 288, 512);
        // pred_next = pred_hidden @ Wf2^T + bf2
        gemm_k<0, 0, ushort_t, ushort_t><<<dim3(rows / 64, 4), 256, 0, stream>>>(
            ph, nullptr, Wf2_b, bf2, pn, 512, 256);
        // forward loss + intrinsic reward
        fl_k<<<rows / 4, 256, 0, stream>>>(pn, outs, (float*)d_out, accp, r0, out_size);
        // mh / sh = relu([sf, pred_next] @ W^T + b)
        gemm_k<2, 1, ushort_t, ushort_t><<<dim3(rows / 64, 8), 256, 0, stream>>>(
            outs + (size_t)r0 * 256, pn, Wm1_b, bm1, mh, 512, 512);
        gemm_k<2, 1, ushort_t, ushort_t><<<dim3(rows / 64, 8), 256, 0, stream>>>(
            outs + (size_t)r0 * 256, pn, Ws1_b, bs1, sh, 512, 512);
        // mu/std heads + inverse loss
        musd_k<<<rows / 8, 256, 0, stream>>>(mh, sh, W2t, bm2, bs2, action, accp + 1, r0);
    }

    // scalars + hidden
    fin_k<<<2048, 256, 0, stream>>>(accp, st, (float*)d_out, out_size);
}

// Round 8
// 7469.626 us; speedup vs baseline: 3.4559x; 3.2913x over previous
//
#include <hip/hip_runtime.h>
#include <hip/hip_bf16.h>

typedef unsigned short ushort_t;
typedef unsigned int   uint_t;

// Problem constants: T1=257, B=512, SD=128, AD=32, HS=512, SF=256, L=2
#define M_ALL 131584   // 257*512
#define M_SEQ 131072   // 256*512

// ---------- helpers ----------
__device__ __forceinline__ float bf2f(ushort_t u) {
    union { uint_t i; float f; } v; v.i = ((uint_t)u) << 16; return v.f;
}
__device__ __forceinline__ float asf(uint_t i) {
    union { uint_t u; float f; } v; v.u = i; return v.f;
}
__device__ __forceinline__ ushort_t f2bf(float f) {
    union { float f; uint_t i; } v; v.f = f;
    uint_t r = v.i + 0x7FFFu + ((v.i >> 16) & 1u);
    return (ushort_t)(r >> 16);
}
__device__ __forceinline__ float fsigm(float x) { return 1.f / (1.f + __expf(-x)); }
__device__ __forceinline__ float ftanh(float x) {
    x = fminf(15.f, fmaxf(-15.f, x));
    float e = __expf(2.f * x);
    return (e - 1.f) / (e + 1.f);
}

typedef __attribute__((ext_vector_type(8))) short  bfrag;   // 8 x bf16
typedef __attribute__((ext_vector_type(4))) float  ffrag;   // 4 x f32 accum

// stage 8 elements into LDS as bf16 (f32 source converts, bf16 source copies)
__device__ __forceinline__ void stage8(const float* p, ushort_t* dst) {
    const float4 a = *(const float4*)p;
    const float4 b = *(const float4*)(p + 4);
    bfrag v;
    v[0] = (short)f2bf(a.x); v[1] = (short)f2bf(a.y);
    v[2] = (short)f2bf(a.z); v[3] = (short)f2bf(a.w);
    v[4] = (short)f2bf(b.x); v[5] = (short)f2bf(b.y);
    v[6] = (short)f2bf(b.z); v[7] = (short)f2bf(b.w);
    *(bfrag*)dst = v;
}
__device__ __forceinline__ void stage8(const ushort_t* p, ushort_t* dst) {
    *(uint4*)dst = *(const uint4*)p;
}

// ---------- generic bf16 MFMA GEMM: C = act(A @ W^T + bias), C bf16, W bf16, bias f32 ----------
// AMODE 0: plain A1 (stride K)
// AMODE 1: k<256 -> A1 stride 256 ; k>=256 -> A2 stride 32  (x = [sf, action])
// AMODE 2: k<256 -> A1 stride 256 ; k>=256 -> A2 stride 256 (xi = [sf, pred_next])
template<int AMODE, int ACT, typename TA1, typename TA2>
__global__ __launch_bounds__(256) void gemm_k(
    const TA1* __restrict__ A1, const TA2* __restrict__ A2,
    const ushort_t* __restrict__ W, const float* __restrict__ b1,
    ushort_t* __restrict__ C, int K, int N)
{
    __shared__ __align__(16) ushort_t As[64][40];
    __shared__ __align__(16) ushort_t Ws[64][40];

    const int tid  = threadIdx.x;
    const int m0   = blockIdx.x * 64;
    const int n0   = blockIdx.y * 64;
    const int lane = tid & 63;
    const int wv   = tid >> 6;
    const int wm   = (wv & 1) * 32;
    const int wn   = (wv >> 1) * 32;
    const int quad = lane >> 4;
    const int ln   = lane & 15;

    ffrag acc[2][2];
#pragma unroll
    for (int i = 0; i < 2; i++)
#pragma unroll
        for (int j = 0; j < 2; j++) acc[i][j] = (ffrag){0.f, 0.f, 0.f, 0.f};

    const int arow = tid >> 2;        // 0..63
    const int acol = (tid & 3) * 8;   // 0,8,16,24

    for (int k0 = 0; k0 < K; k0 += 32) {
        const int kk = k0 + acol;
        if (AMODE == 0) {
            stage8(A1 + (size_t)(m0 + arow) * K + kk, &As[arow][acol]);
        } else if (AMODE == 1) {
            if (kk < 256) stage8(A1 + (size_t)(m0 + arow) * 256 + kk, &As[arow][acol]);
            else          stage8(A2 + (size_t)(m0 + arow) * 32 + (kk - 256), &As[arow][acol]);
        } else {
            if (kk < 256) stage8(A1 + (size_t)(m0 + arow) * 256 + kk, &As[arow][acol]);
            else          stage8(A2 + (size_t)(m0 + arow) * 256 + (kk - 256), &As[arow][acol]);
        }
        stage8(W + (size_t)(n0 + arow) * K + kk, &Ws[arow][acol]);
        __syncthreads();

        bfrag af[2], bfv[2];
#pragma unroll
        for (int i = 0; i < 2; i++) af[i]  = *(const bfrag*)&As[wm + i * 16 + ln][quad * 8];
#pragma unroll
        for (int j = 0; j < 2; j++) bfv[j] = *(const bfrag*)&Ws[wn + j * 16 + ln][quad * 8];
#pragma unroll
        for (int i = 0; i < 2; i++)
#pragma unroll
            for (int j = 0; j < 2; j++)
                acc[i][j] = __builtin_amdgcn_mfma_f32_16x16x32_bf16(af[i], bfv[j], acc[i][j], 0, 0, 0);
        __syncthreads();
    }

#pragma unroll
    for (int j = 0; j < 2; j++) {
        const int n = n0 + wn + j * 16 + ln;
        const float bias = b1[n];
#pragma unroll
        for (int i = 0; i < 2; i++) {
#pragma unroll
            for (int r = 0; r < 4; r++) {
                const int m = m0 + wm + i * 16 + quad * 4 + r;
                float x = acc[i][j][r] + bias;
                if (ACT == 1) x = fmaxf(x, 0.f);
                C[(size_t)m * N + n] = f2bf(x);
            }
        }
    }
}

// ---------- prep: bf16 weights + gate-interleaved recurrent layouts ----------
// wt0[k*1024 + 2u+{0,1}] = Whh0[{i,f}-gate row u][k]; +512 -> {g,o}. Same for wt1 (k>=256: Whh1).
struct PrepArgs {
    const float *Wfe, *Wih0, *Whh0, *bih0, *bhh0, *Wih1, *Whh1, *bih1, *bhh1;
    const float *Wf1, *Wf2, *Wm1, *Ws1, *Wm2, *Ws2;
    ushort_t *Wfe_b, *Wih0_b, *Wih1_b, *wt0, *wt1, *Wf1_b, *Wf2_b, *Wm1_b, *Ws1_b;
    float *W2t, *bias0s, *bias1s;
};
__global__ __launch_bounds__(256) void prep_k(PrepArgs a)
{
    const int idx = blockIdx.x * 256 + threadIdx.x;
    const int stride = gridDim.x * 256;
    for (int e = idx; e < 65536; e += stride)  a.Wfe_b[e]  = f2bf(a.Wfe[e]);
    for (int e = idx; e < 524288; e += stride) a.Wih0_b[e] = f2bf(a.Wih0[e]);   // (1024,512) orig order
    for (int e = idx; e < 262144; e += stride) a.Wih1_b[e] = f2bf(a.Wih1[e]);   // (1024,256) orig order
    for (int e = idx; e < 262144; e += stride) {              // wt0
        const int k = e >> 10, q = e & 1023;
        const int s = q & 1, u = (q >> 1) & 255;
        const int j = ((q >> 9) << 9) + s * 256 + u;
        a.wt0[e] = f2bf(a.Whh0[j * 256 + k]);
    }
    for (int e = idx; e < 524288; e += stride) {              // wt1 (upper half = Whh1 interleave)
        const int k = e >> 10, q = e & 1023;
        const int s = q & 1, u = (q >> 1) & 255;
        const int j = ((q >> 9) << 9) + s * 256 + u;
        a.wt1[e] = f2bf((k < 256) ? a.Wih1[j * 256 + k] : a.Whh1[j * 256 + (k - 256)]);
    }
    for (int e = idx; e < 147456; e += stride) a.Wf1_b[e] = f2bf(a.Wf1[e]);
    for (int e = idx; e < 131072; e += stride) a.Wf2_b[e] = f2bf(a.Wf2[e]);
    for (int e = idx; e < 262144; e += stride) a.Wm1_b[e] = f2bf(a.Wm1[e]);
    for (int e = idx; e < 262144; e += stride) a.Ws1_b[e] = f2bf(a.Ws1[e]);
    for (int e = idx; e < 32768; e += stride) {               // W2t: (512,64) k-major f32
        const int k = e >> 6, c = e & 63;
        a.W2t[e] = (c < 32) ? a.Wm2[c * 512 + k] : a.Ws2[(c - 32) * 512 + k];
    }
    for (int e = idx; e < 1024; e += stride) {
        a.bias0s[e] = a.bih0[e] + a.bhh0[e];
        a.bias1s[e] = a.bih1[e] + a.bhh1[e];
    }
}

// ---------- block-local LSTM scan (NO grid sync): one layer, 256 indep blocks ----------
// Block bid owns batch rows {2bid, 2bid+1}; thread = (row, cell). h,c in registers across
// all ticks; per-tick exchange of the 256-wide h vector via block LDS + __syncthreads.
// Gates' x-part (incl. biases) precomputed in xg (bf16). K=256 recurrent k-loop only.
struct ScanArgs {
    const ushort_t* xg;      // (nsteps*512, 1024) bf16, gate order {i,f,g,o}x256
    const int*      dones;   // (257,512) int32, absolute t indexing
    const ushort_t* wt;      // gate-interleaved recurrent weights (256 k-rows, 1024)
    ushort_t*       hout;    // bf16 h stream: (nsteps*512, 256), chunk-local s indexing
    float*          hst;     // persistent h (512*256 f32)
    float*          cst;     // persistent c (512*256 f32)
    int jc, nsteps, init;
};

__global__ __launch_bounds__(512) void scan_k(ScanArgs a)
{
    __shared__ __align__(16) float xs[2][264];
    const int tid = threadIdx.x;
    const int row = tid >> 8, u = tid & 255;
    const int b = blockIdx.x * 2 + row;
    float h = a.init ? 0.f : a.hst[b * 256 + u];
    float c = a.init ? 0.f : a.cst[b * 256 + u];
    const ushort_t* wtu = a.wt + 2 * u;

    for (int sst = 0; sst < a.nsteps; ++sst) {
        const int t = a.jc + sst;
        const float m = 1.f - (float)a.dones[t * 512 + b];
        xs[row][u] = h * m;
        __syncthreads();
        const size_t base = ((size_t)sst * 512 + b) * 1024;
        float ai = bf2f(a.xg[base + u]),       af = bf2f(a.xg[base + 256 + u]);
        float ag = bf2f(a.xg[base + 512 + u]), ao = bf2f(a.xg[base + 768 + u]);
        for (int k0 = 0; k0 < 256; k0 += 8) {
            uint_t pif[8], pgo[8];
#pragma unroll
            for (int e = 0; e < 8; e++) {
                pif[e] = *(const uint_t*)(wtu + ((k0 + e) << 10));
                pgo[e] = *(const uint_t*)(wtu + ((k0 + e) << 10) + 512);
            }
            float hr[8];
            *(float4*)&hr[0] = *(const float4*)&xs[row][k0];
            *(float4*)&hr[4] = *(const float4*)&xs[row][k0 + 4];
#pragma unroll
            for (int e = 0; e < 8; e++) {
                const float wi = asf(pif[e] << 16), wf = asf(pif[e] & 0xFFFF0000u);
                const float wg = asf(pgo[e] << 16), wo = asf(pgo[e] & 0xFFFF0000u);
                ai += hr[e] * wi; af += hr[e] * wf; ag += hr[e] * wg; ao += hr[e] * wo;
            }
        }
        const float cold = c * m;
        const float c2 = fsigm(af) * cold + fsigm(ai) * ftanh(ag);
        const float h2 = fsigm(ao) * ftanh(c2);
        c = c2; h = h2;
        a.hout[((size_t)sst * 512 + b) * 256 + u] = f2bf(h2);
        __syncthreads();
    }
    a.hst[b * 256 + u] = h;
    a.cst[b * 256 + u] = c;
}

// ---------- forward loss + intrinsic reward (row-chunked), f32 out ----------
__global__ __launch_bounds__(256) void fl_k(const ushort_t* __restrict__ pn,
                                            const ushort_t* __restrict__ outs,
                                            float* __restrict__ out, float* __restrict__ acc,
                                            int r0, int out_size)
{
    __shared__ float bs[4];
    const int tid = threadIdx.x;
    const int w = tid >> 6, l = tid & 63;
    const size_t rl = (size_t)blockIdx.x * 4 + w;
    const size_t rg = rl + r0;
    const ushort_t* p = pn + rl * 256;
    const ushort_t* q = outs + (rg + 512) * 256;   // next_state_features = outs[t+1]
    float s = 0.f;
#pragma unroll
    for (int i = 0; i < 4; i++) {
        const float d = bf2f(p[l + i * 64]) - bf2f(q[l + i * 64]);
        s += d * d;
    }
#pragma unroll
    for (int off = 32; off > 0; off >>= 1) s += __shfl_down(s, off);
    if (l == 0) { if ((long long)(2 + rg) < out_size) out[2 + rg] = s; bs[w] = s; }
    __syncthreads();
    if (tid == 0) atomicAdd(acc, bs[0] + bs[1] + bs[2] + bs[3]);
}

// ---------- fused mu/std heads + inverse loss (row-chunked), coalesced W2t ----------
__global__ __launch_bounds__(256) void musd_k(
    const ushort_t* __restrict__ mh, const ushort_t* __restrict__ sh,
    const float* __restrict__ W2t, const float* __restrict__ bm2,
    const float* __restrict__ bs2, const float* __restrict__ action,
    float* __restrict__ acc, int r0)
{
    __shared__ __align__(16) ushort_t mhs[8][512];
    __shared__ __align__(16) ushort_t shs[8][512];
    __shared__ float red[256];
    const int tid = threadIdx.x;
    const size_t rl0 = (size_t)blockIdx.x * 8;
    for (int i = tid; i < 512; i += 256) {
        const int row = i >> 6, c = (i & 63) * 8;
        *(uint4*)&mhs[row][c] = *(const uint4*)&mh[(rl0 + row) * 512 + c];
        *(uint4*)&shs[row][c] = *(const uint4*)&sh[(rl0 + row) * 512 + c];
    }
    __syncthreads();
    const int row = tid >> 5, c = tid & 31;
    float am = bm2[c], asv = bs2[c];
    for (int k = 0; k < 512; k += 8) {
#pragma unroll
        for (int e = 0; e < 8; e++) {
            const float wm = W2t[(k + e) * 64 + c];
            const float wsv = W2t[(k + e) * 64 + 32 + c];
            am  += bf2f(mhs[row][k + e]) * wm;
            asv += bf2f(shs[row][k + e]) * wsv;
        }
    }
    const float mu = ftanh(am);
    const float sp = fmaxf(asv, 0.f) + log1pf(__expf(-fabsf(asv)));   // softplus
    const float a  = action[(rl0 + r0 + row) * 32 + c];
    const float z  = (a - mu) / sp;
    red[tid] = 0.5f * z * z + __logf(sp) + 0.918938533204672741f;     // -log_prob
    __syncthreads();
    for (int s = 128; s > 0; s >>= 1) { if (tid < s) red[tid] += red[tid + s]; __syncthreads(); }
    if (tid == 0) atomicAdd(acc, red[0]);
}

// ---------- finalize: scalar losses + hidden copy-out (f32) ----------
__global__ __launch_bounds__(256) void fin_k(const float* __restrict__ acc,
                                             const float* __restrict__ h0st,
                                             const float* __restrict__ h1st,
                                             const float* __restrict__ c0st,
                                             const float* __restrict__ c1st,
                                             float* __restrict__ out, int out_size)
{
    const size_t idx = (size_t)blockIdx.x * 256 + threadIdx.x;
    if (idx == 0 && out_size > 0) out[0] = acc[0] / 33554432.f;   // mean over 256*512*256
    if (idx == 1 && out_size > 1) out[1] = acc[1] / 4194304.f;    // mean over 256*512*32
    if (idx < 524288) {
        const int which = (int)(idx >> 17);
        const int local = (int)(idx & 131071);
        float v;
        if      (which == 0) v = h0st[local];
        else if (which == 1) v = h1st[local];
        else if (which == 2) v = c0st[local];
        else                 v = c1st[local];
        const size_t o = 2 + 131072 + idx;
        if ((long long)o < out_size) out[o] = v;
    }
}

extern "C" void kernel_launch(void* const* d_in, const int* in_sizes, int n_in,
                              void* d_out, int out_size, void* d_ws, size_t ws_size,
                              hipStream_t stream)
{
    const float* states = (const float*)d_in[0];
    const float* action = (const float*)d_in[1];
    const int*   dones  = (const int*)d_in[2];
    const float* Wfe  = (const float*)d_in[3];
    const float* bfe  = (const float*)d_in[4];
    const float* Wih0 = (const float*)d_in[5];
    const float* Whh0 = (const float*)d_in[6];
    const float* bih0 = (const float*)d_in[7];
    const float* bhh0 = (const float*)d_in[8];
    const float* Wih1 = (const float*)d_in[9];
    const float* Whh1 = (const float*)d_in[10];
    const float* bih1 = (const float*)d_in[11];
    const float* bhh1 = (const float*)d_in[12];
    const float* Wf1  = (const float*)d_in[13];
    const float* bf1  = (const float*)d_in[14];
    const float* Wf2  = (const float*)d_in[15];
    const float* bf2  = (const float*)d_in[16];
    const float* Wm1  = (const float*)d_in[17];
    const float* bm1  = (const float*)d_in[18];
    const float* Wm2  = (const float*)d_in[19];
    const float* bm2  = (const float*)d_in[20];
    const float* Ws1  = (const float*)d_in[21];
    const float* bs1  = (const float*)d_in[22];
    const float* Ws2  = (const float*)d_in[23];
    const float* bs2  = (const float*)d_in[24];

    // ---------- workspace layout (persistent region) ----------
    char* ws = (char*)d_ws;
    size_t off = 0;
    ushort_t* outs    = (ushort_t*)(ws + off); off += 67371008;  // 257*512*256 bf16
    float*    h0st    = (float*)(ws + off);    off += 524288;    // 512*256 f32
    float*    c0st    = (float*)(ws + off);    off += 524288;
    float*    h1st    = (float*)(ws + off);    off += 524288;
    float*    c1st    = (float*)(ws + off);    off += 524288;
    ushort_t* wt0     = (ushort_t*)(ws + off); off += 524288;
    ushort_t* wt1     = (ushort_t*)(ws + off); off += 1048576;
    ushort_t* Wfe_b   = (ushort_t*)(ws + off); off += 131072;
    ushort_t* Wih0_b  = (ushort_t*)(ws + off); off += 1048576;
    ushort_t* Wih1_b  = (ushort_t*)(ws + off); off += 524288;
    ushort_t* Wf1_b   = (ushort_t*)(ws + off); off += 294912;
    ushort_t* Wf2_b   = (ushort_t*)(ws + off); off += 262144;
    ushort_t* Wm1_b   = (ushort_t*)(ws + off); off += 524288;
    ushort_t* Ws1_b   = (ushort_t*)(ws + off); off += 524288;
    float*    W2t     = (float*)(ws + off);    off += 131072;
    float*    bias0s  = (float*)(ws + off);    off += 4096;
    float*    bias1s  = (float*)(ws + off);    off += 4096;
    float*    accp    = (float*)(ws + off);    off += 256;
    char*     S       = ws + off;              // chunk scratch
    const size_t avail = (ws_size > off) ? (ws_size - off) : 0;

    // scan-phase chunk budget per step (bytes):
    //   feats bf16 524288 + xg0 bf16 1048576 + h0s bf16 262144 + xg1 bf16 1048576
    const size_t STEP_B = 2883584;
    int TC = (int)(avail / STEP_B);
    if (TC > 257) TC = 257;
    if (TC < 1)   TC = 1;
    // head-phase chunk: per row ph(1024)+pn(512)+mh(1024)+sh(1024) bytes (bf16)
    long long rc = (long long)(avail / 3584) & ~63LL;
    if (rc > 131072) rc = 131072;
    if (rc < 64)     rc = 64;
    const int RC = (int)rc;

    hipMemsetAsync(accp, 0, 256, stream);

    PrepArgs pa{ Wfe, Wih0, Whh0, bih0, bhh0, Wih1, Whh1, bih1, bhh1,
                 Wf1, Wf2, Wm1, Ws1, Wm2, Ws2,
                 Wfe_b, Wih0_b, Wih1_b, wt0, wt1, Wf1_b, Wf2_b, Wm1_b, Ws1_b,
                 W2t, bias0s, bias1s };
    prep_k<<<512, 256, 0, stream>>>(pa);

    // ---------- scan phase (time-chunked, no grid sync anywhere) ----------
    ushort_t* featsck = (ushort_t*)S;
    ushort_t* xg0ck   = (ushort_t*)(S + (size_t)TC * 524288);
    ushort_t* h0sck   = (ushort_t*)(S + (size_t)TC * 1572864);
    ushort_t* xg1ck   = (ushort_t*)(S + (size_t)TC * 1835008);
    for (int jc = 0; jc < 257; jc += TC) {
        const int nsteps = (257 - jc < TC) ? (257 - jc) : TC;
        // feats = relu(states_chunk @ Wfe^T + bfe)
        gemm_k<0, 1, float, float><<<dim3(nsteps * 8, 8), 256, 0, stream>>>(
            states + (size_t)jc * 512 * 128, nullptr, Wfe_b, bfe, featsck, 128, 512);
        // xg0 = feats @ Wih0^T + (bih0 + bhh0)
        gemm_k<0, 0, ushort_t, ushort_t><<<dim3(nsteps * 8, 16), 256, 0, stream>>>(
            featsck, nullptr, Wih0_b, bias0s, xg0ck, 512, 1024);
        // layer-0 scan: block-local recurrence over [jc, jc+nsteps)
        ScanArgs sa0{ xg0ck, dones, wt0, h0sck, h0st, c0st, jc, nsteps, (jc == 0) ? 1 : 0 };
        scan_k<<<256, 512, 0, stream>>>(sa0);
        // xg1 = h0s @ Wih1^T + (bih1 + bhh1)
        gemm_k<0, 0, ushort_t, ushort_t><<<dim3(nsteps * 8, 16), 256, 0, stream>>>(
            h0sck, nullptr, Wih1_b, bias1s, xg1ck, 256, 1024);
        // layer-1 scan: consumes xg1, recurrent part = Whh1 (wt1 upper half)
        ScanArgs sa1{ xg1ck, dones, wt1 + 262144, outs + (size_t)jc * 131072,
                      h1st, c1st, jc, nsteps, (jc == 0) ? 1 : 0 };
        scan_k<<<256, 512, 0, stream>>>(sa1);
    }

    // ---------- head phase (row-chunked) ----------
    for (int r0 = 0; r0 < M_SEQ; r0 += RC) {
        const int rows = (M_SEQ - r0 < RC) ? (M_SEQ - r0) : RC;
        ushort_t* ph = (ushort_t*)S;
        ushort_t* pn = (ushort_t*)(S + (size_t)rows * 1024);
        ushort_t* mh = (ushort_t*)(S + (size_t)rows * 1536);
        ushort_t* sh = (ushort_t*)(S + (size_t)rows * 2560);
        // pred_hidden = relu([sf, action] @ Wf1^T + bf1)
        gemm_k<1, 1, ushort_t, float><<<dim3(rows / 64, 8), 256, 0, stream>>>(
            outs + (size_t)r0 * 256, action + (size_t)r0 * 32, Wf1_b, bf1, ph, 288, 512);
        // pred_next = pred_hidden @ Wf2^T + bf2
        gemm_k<0, 0, ushort_t, ushort_t><<<dim3(rows / 64, 4), 256, 0, stream>>>(
            ph, nullptr, Wf2_b, bf2, pn, 512, 256);
        // forward loss + intrinsic reward
        fl_k<<<rows / 4, 256, 0, stream>>>(pn, outs, (float*)d_out, accp, r0, out_size);
        // mh / sh = relu([sf, pred_next] @ W^T + b)
        gemm_k<2, 1, ushort_t, ushort_t><<<dim3(rows / 64, 8), 256, 0, stream>>>(
            outs + (size_t)r0 * 256, pn, Wm1_b, bm1, mh, 512, 512);
        gemm_k<2, 1, ushort_t, ushort_t><<<dim3(rows / 64, 8), 256, 0, stream>>>(
            outs + (size_t)r0 * 256, pn, Ws1_b, bs1, sh, 512, 512);
        // mu/std heads + inverse loss
        musd_k<<<rows / 8, 256, 0, stream>>>(mh, sh, W2t, bm2, bs2, action, accp + 1, r0);
    }

    // scalars + hidden
    fin_k<<<2048, 256, 0, stream>>>(accp, h0st, h1st, c0st, c1st, (float*)d_out, out_size);
}

// Round 9
// 7416.216 us; speedup vs baseline: 3.4808x; 1.0072x over previous
//
#include <hip/hip_runtime.h>
#include <hip/hip_bf16.h>

typedef unsigned short ushort_t;
typedef unsigned int   uint_t;

// Problem constants: T1=257, B=512, SD=128, AD=32, HS=512, SF=256, L=2
#define M_ALL 131584   // 257*512
#define M_SEQ 131072   // 256*512

// ---------- helpers ----------
__device__ __forceinline__ float bf2f(ushort_t u) {
    union { uint_t i; float f; } v; v.i = ((uint_t)u) << 16; return v.f;
}
__device__ __forceinline__ float asf(uint_t i) {
    union { uint_t u; float f; } v; v.u = i; return v.f;
}
__device__ __forceinline__ ushort_t f2bf(float f) {
    union { float f; uint_t i; } v; v.f = f;
    uint_t r = v.i + 0x7FFFu + ((v.i >> 16) & 1u);
    return (ushort_t)(r >> 16);
}
__device__ __forceinline__ float fsigm(float x) { return 1.f / (1.f + __expf(-x)); }
__device__ __forceinline__ float ftanh(float x) {
    x = fminf(15.f, fmaxf(-15.f, x));
    float e = __expf(2.f * x);
    return (e - 1.f) / (e + 1.f);
}

typedef __attribute__((ext_vector_type(8))) short  bfrag;   // 8 x bf16
typedef __attribute__((ext_vector_type(4))) float  ffrag;   // 4 x f32 accum

// stage 8 elements into LDS as bf16 (f32 source converts, bf16 source copies)
__device__ __forceinline__ void stage8(const float* p, ushort_t* dst) {
    const float4 a = *(const float4*)p;
    const float4 b = *(const float4*)(p + 4);
    bfrag v;
    v[0] = (short)f2bf(a.x); v[1] = (short)f2bf(a.y);
    v[2] = (short)f2bf(a.z); v[3] = (short)f2bf(a.w);
    v[4] = (short)f2bf(b.x); v[5] = (short)f2bf(b.y);
    v[6] = (short)f2bf(b.z); v[7] = (short)f2bf(b.w);
    *(bfrag*)dst = v;
}
__device__ __forceinline__ void stage8(const ushort_t* p, ushort_t* dst) {
    *(uint4*)dst = *(const uint4*)p;
}

// ---------- 128x128-tile bf16 MFMA GEMM: C = act(A @ W^T + bias), C bf16, W bf16, bias f32 ----------
// 256 threads = 4 waves in 2x2; each wave computes 64x64 via 4x4 MFMA(16x16x32) tiles.
// AMODE 0: plain A1 (stride K)
// AMODE 1: k<256 -> A1 stride 256 ; k>=256 -> A2 stride 32  (x = [sf, action])
// AMODE 2: k<256 -> A1 stride 256 ; k>=256 -> A2 stride 256 (xi = [sf, pred_next])
template<int AMODE, int ACT, typename TA1, typename TA2>
__global__ __launch_bounds__(256) void gemm_k(
    const TA1* __restrict__ A1, const TA2* __restrict__ A2,
    const ushort_t* __restrict__ W, const float* __restrict__ b1,
    ushort_t* __restrict__ C, int K, int N)
{
    __shared__ __align__(16) ushort_t As[128][40];   // 40-short rows: 80B = 5x16B (aligned b128)
    __shared__ __align__(16) ushort_t Ws[128][40];

    const int tid  = threadIdx.x;
    const int m0   = blockIdx.x * 128;
    const int n0   = blockIdx.y * 128;
    const int lane = tid & 63;
    const int wv   = tid >> 6;
    const int wm   = (wv & 1) * 64;
    const int wn   = (wv >> 1) * 64;
    const int quad = lane >> 4;
    const int ln   = lane & 15;

    ffrag acc[4][4];
#pragma unroll
    for (int i = 0; i < 4; i++)
#pragma unroll
        for (int j = 0; j < 4; j++) acc[i][j] = (ffrag){0.f, 0.f, 0.f, 0.f};

    const int arow = tid >> 2;        // 0..63 (stages rows arow, arow+64)
    const int acol = (tid & 3) * 8;   // 0,8,16,24

    for (int k0 = 0; k0 < K; k0 += 32) {
        const int kk = k0 + acol;
#pragma unroll
        for (int rr = 0; rr < 2; rr++) {
            const int row = arow + rr * 64;
            if (AMODE == 0) {
                stage8(A1 + (size_t)(m0 + row) * K + kk, &As[row][acol]);
            } else if (AMODE == 1) {
                if (kk < 256) stage8(A1 + (size_t)(m0 + row) * 256 + kk, &As[row][acol]);
                else          stage8(A2 + (size_t)(m0 + row) * 32 + (kk - 256), &As[row][acol]);
            } else {
                if (kk < 256) stage8(A1 + (size_t)(m0 + row) * 256 + kk, &As[row][acol]);
                else          stage8(A2 + (size_t)(m0 + row) * 256 + (kk - 256), &As[row][acol]);
            }
            stage8(W + (size_t)(n0 + row) * K + kk, &Ws[row][acol]);
        }
        __syncthreads();

        bfrag af[4], bfv[4];
#pragma unroll
        for (int i = 0; i < 4; i++) af[i]  = *(const bfrag*)&As[wm + i * 16 + ln][quad * 8];
#pragma unroll
        for (int j = 0; j < 4; j++) bfv[j] = *(const bfrag*)&Ws[wn + j * 16 + ln][quad * 8];
#pragma unroll
        for (int i = 0; i < 4; i++)
#pragma unroll
            for (int j = 0; j < 4; j++)
                acc[i][j] = __builtin_amdgcn_mfma_f32_16x16x32_bf16(af[i], bfv[j], acc[i][j], 0, 0, 0);
        __syncthreads();
    }

#pragma unroll
    for (int j = 0; j < 4; j++) {
        const int n = n0 + wn + j * 16 + ln;
        const float bias = b1[n];
#pragma unroll
        for (int i = 0; i < 4; i++) {
#pragma unroll
            for (int r = 0; r < 4; r++) {
                const int m = m0 + wm + i * 16 + quad * 4 + r;
                float x = acc[i][j][r] + bias;
                if (ACT == 1) x = fmaxf(x, 0.f);
                C[(size_t)m * N + n] = f2bf(x);
            }
        }
    }
}

// ---------- prep: bf16 weights + gate-interleaved recurrent layouts ----------
// wt0[k*1024 + 2u+{0,1}] = Whh0[{i,f}-gate row u][k]; +512 -> {g,o}. Same for wt1 (k>=256: Whh1).
struct PrepArgs {
    const float *Wfe, *Wih0, *Whh0, *bih0, *bhh0, *Wih1, *Whh1, *bih1, *bhh1;
    const float *Wf1, *Wf2, *Wm1, *Ws1, *Wm2, *Ws2;
    ushort_t *Wfe_b, *Wih0_b, *Wih1_b, *wt0, *wt1, *Wf1_b, *Wf2_b, *Wm1_b, *Ws1_b;
    float *W2t, *bias0s, *bias1s;
};
__global__ __launch_bounds__(256) void prep_k(PrepArgs a)
{
    const int idx = blockIdx.x * 256 + threadIdx.x;
    const int stride = gridDim.x * 256;
    for (int e = idx; e < 65536; e += stride)  a.Wfe_b[e]  = f2bf(a.Wfe[e]);
    for (int e = idx; e < 524288; e += stride) a.Wih0_b[e] = f2bf(a.Wih0[e]);   // (1024,512) orig order
    for (int e = idx; e < 262144; e += stride) a.Wih1_b[e] = f2bf(a.Wih1[e]);   // (1024,256) orig order
    for (int e = idx; e < 262144; e += stride) {              // wt0
        const int k = e >> 10, q = e & 1023;
        const int s = q & 1, u = (q >> 1) & 255;
        const int j = ((q >> 9) << 9) + s * 256 + u;
        a.wt0[e] = f2bf(a.Whh0[j * 256 + k]);
    }
    for (int e = idx; e < 524288; e += stride) {              // wt1 (upper half = Whh1 interleave)
        const int k = e >> 10, q = e & 1023;
        const int s = q & 1, u = (q >> 1) & 255;
        const int j = ((q >> 9) << 9) + s * 256 + u;
        a.wt1[e] = f2bf((k < 256) ? a.Wih1[j * 256 + k] : a.Whh1[j * 256 + (k - 256)]);
    }
    for (int e = idx; e < 147456; e += stride) a.Wf1_b[e] = f2bf(a.Wf1[e]);
    for (int e = idx; e < 131072; e += stride) a.Wf2_b[e] = f2bf(a.Wf2[e]);
    for (int e = idx; e < 262144; e += stride) a.Wm1_b[e] = f2bf(a.Wm1[e]);
    for (int e = idx; e < 262144; e += stride) a.Ws1_b[e] = f2bf(a.Ws1[e]);
    for (int e = idx; e < 32768; e += stride) {               // W2t: (512,64) k-major f32
        const int k = e >> 6, c = e & 63;
        a.W2t[e] = (c < 32) ? a.Wm2[c * 512 + k] : a.Ws2[(c - 32) * 512 + k];
    }
    for (int e = idx; e < 1024; e += stride) {
        a.bias0s[e] = a.bih0[e] + a.bhh0[e];
        a.bias1s[e] = a.bih1[e] + a.bhh1[e];
    }
}

// ---------- block-local LSTM scan (NO grid sync): one layer, 256 indep blocks ----------
struct ScanArgs {
    const ushort_t* xg;      // (nsteps*512, 1024) bf16, gate order {i,f,g,o}x256
    const int*      dones;   // (257,512) int32, absolute t indexing
    const ushort_t* wt;      // gate-interleaved recurrent weights (256 k-rows, 1024)
    ushort_t*       hout;    // bf16 h stream: (nsteps*512, 256), chunk-local s indexing
    float*          hst;     // persistent h (512*256 f32)
    float*          cst;     // persistent c (512*256 f32)
    int jc, nsteps, init;
};

__global__ __launch_bounds__(512) void scan_k(ScanArgs a)
{
    __shared__ __align__(16) float xs[2][264];
    const int tid = threadIdx.x;
    const int row = tid >> 8, u = tid & 255;
    const int b = blockIdx.x * 2 + row;
    float h = a.init ? 0.f : a.hst[b * 256 + u];
    float c = a.init ? 0.f : a.cst[b * 256 + u];
    const ushort_t* wtu = a.wt + 2 * u;

    for (int sst = 0; sst < a.nsteps; ++sst) {
        const int t = a.jc + sst;
        const float m = 1.f - (float)a.dones[t * 512 + b];
        xs[row][u] = h * m;
        __syncthreads();
        const size_t base = ((size_t)sst * 512 + b) * 1024;
        float ai = bf2f(a.xg[base + u]),       af = bf2f(a.xg[base + 256 + u]);
        float ag = bf2f(a.xg[base + 512 + u]), ao = bf2f(a.xg[base + 768 + u]);
        for (int k0 = 0; k0 < 256; k0 += 8) {
            uint_t pif[8], pgo[8];
#pragma unroll
            for (int e = 0; e < 8; e++) {
                pif[e] = *(const uint_t*)(wtu + ((k0 + e) << 10));
                pgo[e] = *(const uint_t*)(wtu + ((k0 + e) << 10) + 512);
            }
            float hr[8];
            *(float4*)&hr[0] = *(const float4*)&xs[row][k0];
            *(float4*)&hr[4] = *(const float4*)&xs[row][k0 + 4];
#pragma unroll
            for (int e = 0; e < 8; e++) {
                const float wi = asf(pif[e] << 16), wf = asf(pif[e] & 0xFFFF0000u);
                const float wg = asf(pgo[e] << 16), wo = asf(pgo[e] & 0xFFFF0000u);
                ai += hr[e] * wi; af += hr[e] * wf; ag += hr[e] * wg; ao += hr[e] * wo;
            }
        }
        const float cold = c * m;
        const float c2 = fsigm(af) * cold + fsigm(ai) * ftanh(ag);
        const float h2 = fsigm(ao) * ftanh(c2);
        c = c2; h = h2;
        a.hout[((size_t)sst * 512 + b) * 256 + u] = f2bf(h2);
        __syncthreads();
    }
    a.hst[b * 256 + u] = h;
    a.cst[b * 256 + u] = c;
}

// ---------- forward loss + intrinsic reward (row-chunked), f32 out ----------
__global__ __launch_bounds__(256) void fl_k(const ushort_t* __restrict__ pn,
                                            const ushort_t* __restrict__ outs,
                                            float* __restrict__ out, float* __restrict__ acc,
                                            int r0, int out_size)
{
    __shared__ float bs[4];
    const int tid = threadIdx.x;
    const int w = tid >> 6, l = tid & 63;
    const size_t rl = (size_t)blockIdx.x * 4 + w;
    const size_t rg = rl + r0;
    const ushort_t* p = pn + rl * 256;
    const ushort_t* q = outs + (rg + 512) * 256;   // next_state_features = outs[t+1]
    float s = 0.f;
#pragma unroll
    for (int i = 0; i < 4; i++) {
        const float d = bf2f(p[l + i * 64]) - bf2f(q[l + i * 64]);
        s += d * d;
    }
#pragma unroll
    for (int off = 32; off > 0; off >>= 1) s += __shfl_down(s, off);
    if (l == 0) { if ((long long)(2 + rg) < out_size) out[2 + rg] = s; bs[w] = s; }
    __syncthreads();
    if (tid == 0) atomicAdd(acc, bs[0] + bs[1] + bs[2] + bs[3]);
}

// ---------- fused mu/std heads + inverse loss (row-chunked), coalesced W2t ----------
__global__ __launch_bounds__(256) void musd_k(
    const ushort_t* __restrict__ mh, const ushort_t* __restrict__ sh,
    const float* __restrict__ W2t, const float* __restrict__ bm2,
    const float* __restrict__ bs2, const float* __restrict__ action,
    float* __restrict__ acc, int r0)
{
    __shared__ __align__(16) ushort_t mhs[8][512];
    __shared__ __align__(16) ushort_t shs[8][512];
    __shared__ float red[256];
    const int tid = threadIdx.x;
    const size_t rl0 = (size_t)blockIdx.x * 8;
    for (int i = tid; i < 512; i += 256) {
        const int row = i >> 6, c = (i & 63) * 8;
        *(uint4*)&mhs[row][c] = *(const uint4*)&mh[(rl0 + row) * 512 + c];
        *(uint4*)&shs[row][c] = *(const uint4*)&sh[(rl0 + row) * 512 + c];
    }
    __syncthreads();
    const int row = tid >> 5, c = tid & 31;
    float am = bm2[c], asv = bs2[c];
    for (int k = 0; k < 512; k += 8) {
#pragma unroll
        for (int e = 0; e < 8; e++) {
            const float wm = W2t[(k + e) * 64 + c];
            const float wsv = W2t[(k + e) * 64 + 32 + c];
            am  += bf2f(mhs[row][k + e]) * wm;
            asv += bf2f(shs[row][k + e]) * wsv;
        }
    }
    const float mu = ftanh(am);
    const float sp = fmaxf(asv, 0.f) + log1pf(__expf(-fabsf(asv)));   // softplus
    const float a  = action[(rl0 + r0 + row) * 32 + c];
    const float z  = (a - mu) / sp;
    red[tid] = 0.5f * z * z + __logf(sp) + 0.918938533204672741f;     // -log_prob
    __syncthreads();
    for (int s = 128; s > 0; s >>= 1) { if (tid < s) red[tid] += red[tid + s]; __syncthreads(); }
    if (tid == 0) atomicAdd(acc, red[0]);
}

// ---------- finalize: scalar losses + hidden copy-out (f32) ----------
__global__ __launch_bounds__(256) void fin_k(const float* __restrict__ acc,
                                             const float* __restrict__ h0st,
                                             const float* __restrict__ h1st,
                                             const float* __restrict__ c0st,
                                             const float* __restrict__ c1st,
                                             float* __restrict__ out, int out_size)
{
    const size_t idx = (size_t)blockIdx.x * 256 + threadIdx.x;
    if (idx == 0 && out_size > 0) out[0] = acc[0] / 33554432.f;   // mean over 256*512*256
    if (idx == 1 && out_size > 1) out[1] = acc[1] / 4194304.f;    // mean over 256*512*32
    if (idx < 524288) {
        const int which = (int)(idx >> 17);
        const int local = (int)(idx & 131071);
        float v;
        if      (which == 0) v = h0st[local];
        else if (which == 1) v = h1st[local];
        else if (which == 2) v = c0st[local];
        else                 v = c1st[local];
        const size_t o = 2 + 131072 + idx;
        if ((long long)o < out_size) out[o] = v;
    }
}

extern "C" void kernel_launch(void* const* d_in, const int* in_sizes, int n_in,
                              void* d_out, int out_size, void* d_ws, size_t ws_size,
                              hipStream_t stream)
{
    const float* states = (const float*)d_in[0];
    const float* action = (const float*)d_in[1];
    const int*   dones  = (const int*)d_in[2];
    const float* Wfe  = (const float*)d_in[3];
    const float* bfe  = (const float*)d_in[4];
    const float* Wih0 = (const float*)d_in[5];
    const float* Whh0 = (const float*)d_in[6];
    const float* bih0 = (const float*)d_in[7];
    const float* bhh0 = (const float*)d_in[8];
    const float* Wih1 = (const float*)d_in[9];
    const float* Whh1 = (const float*)d_in[10];
    const float* bih1 = (const float*)d_in[11];
    const float* bhh1 = (const float*)d_in[12];
    const float* Wf1  = (const float*)d_in[13];
    const float* bf1  = (const float*)d_in[14];
    const float* Wf2  = (const float*)d_in[15];
    const float* bf2  = (const float*)d_in[16];
    const float* Wm1  = (const float*)d_in[17];
    const float* bm1  = (const float*)d_in[18];
    const float* Wm2  = (const float*)d_in[19];
    const float* bm2  = (const float*)d_in[20];
    const float* Ws1  = (const float*)d_in[21];
    const float* bs1  = (const float*)d_in[22];
    const float* Ws2  = (const float*)d_in[23];
    const float* bs2  = (const float*)d_in[24];

    // ---------- workspace layout (persistent region) ----------
    char* ws = (char*)d_ws;
    size_t off = 0;
    ushort_t* outs    = (ushort_t*)(ws + off); off += 67371008;  // 257*512*256 bf16
    float*    h0st    = (float*)(ws + off);    off += 524288;    // 512*256 f32
    float*    c0st    = (float*)(ws + off);    off += 524288;
    float*    h1st    = (float*)(ws + off);    off += 524288;
    float*    c1st    = (float*)(ws + off);    off += 524288;
    ushort_t* wt0     = (ushort_t*)(ws + off); off += 524288;
    ushort_t* wt1     = (ushort_t*)(ws + off); off += 1048576;
    ushort_t* Wfe_b   = (ushort_t*)(ws + off); off += 131072;
    ushort_t* Wih0_b  = (ushort_t*)(ws + off); off += 1048576;
    ushort_t* Wih1_b  = (ushort_t*)(ws + off); off += 524288;
    ushort_t* Wf1_b   = (ushort_t*)(ws + off); off += 294912;
    ushort_t* Wf2_b   = (ushort_t*)(ws + off); off += 262144;
    ushort_t* Wm1_b   = (ushort_t*)(ws + off); off += 524288;
    ushort_t* Ws1_b   = (ushort_t*)(ws + off); off += 524288;
    float*    W2t     = (float*)(ws + off);    off += 131072;
    float*    bias0s  = (float*)(ws + off);    off += 4096;
    float*    bias1s  = (float*)(ws + off);    off += 4096;
    float*    accp    = (float*)(ws + off);    off += 256;
    char*     S       = ws + off;              // chunk scratch
    const size_t avail = (ws_size > off) ? (ws_size - off) : 0;

    // scan-phase chunk budget per step (bytes):
    //   feats bf16 524288 + xg0 bf16 1048576 + h0s bf16 262144 + xg1 bf16 1048576
    const size_t STEP_B = 2883584;
    int TC = (int)(avail / STEP_B);
    if (TC > 257) TC = 257;
    if (TC < 1)   TC = 1;
    // head-phase chunk: per row ph(1024)+pn(512)+mh(1024)+sh(1024) bytes (bf16), 128-aligned rows
    long long rc = (long long)(avail / 3584) & ~127LL;
    if (rc > 131072) rc = 131072;
    if (rc < 128)    rc = 128;
    const int RC = (int)rc;

    hipMemsetAsync(accp, 0, 256, stream);

    PrepArgs pa{ Wfe, Wih0, Whh0, bih0, bhh0, Wih1, Whh1, bih1, bhh1,
                 Wf1, Wf2, Wm1, Ws1, Wm2, Ws2,
                 Wfe_b, Wih0_b, Wih1_b, wt0, wt1, Wf1_b, Wf2_b, Wm1_b, Ws1_b,
                 W2t, bias0s, bias1s };
    prep_k<<<512, 256, 0, stream>>>(pa);

    // ---------- scan phase (time-chunked, no grid sync anywhere) ----------
    ushort_t* featsck = (ushort_t*)S;
    ushort_t* xg0ck   = (ushort_t*)(S + (size_t)TC * 524288);
    ushort_t* h0sck   = (ushort_t*)(S + (size_t)TC * 1572864);
    ushort_t* xg1ck   = (ushort_t*)(S + (size_t)TC * 1835008);
    for (int jc = 0; jc < 257; jc += TC) {
        const int nsteps = (257 - jc < TC) ? (257 - jc) : TC;
        // feats = relu(states_chunk @ Wfe^T + bfe)      [M=nsteps*512, N=512, K=128]
        gemm_k<0, 1, float, float><<<dim3(nsteps * 4, 4), 256, 0, stream>>>(
            states + (size_t)jc * 512 * 128, nullptr, Wfe_b, bfe, featsck, 128, 512);
        // xg0 = feats @ Wih0^T + (bih0 + bhh0)          [N=1024, K=512]
        gemm_k<0, 0, ushort_t, ushort_t><<<dim3(nsteps * 4, 8), 256, 0, stream>>>(
            featsck, nullptr, Wih0_b, bias0s, xg0ck, 512, 1024);
        // layer-0 scan: block-local recurrence over [jc, jc+nsteps)
        ScanArgs sa0{ xg0ck, dones, wt0, h0sck, h0st, c0st, jc, nsteps, (jc == 0) ? 1 : 0 };
        scan_k<<<256, 512, 0, stream>>>(sa0);
        // xg1 = h0s @ Wih1^T + (bih1 + bhh1)            [N=1024, K=256]
        gemm_k<0, 0, ushort_t, ushort_t><<<dim3(nsteps * 4, 8), 256, 0, stream>>>(
            h0sck, nullptr, Wih1_b, bias1s, xg1ck, 256, 1024);
        // layer-1 scan: consumes xg1, recurrent part = Whh1 (wt1 upper half)
        ScanArgs sa1{ xg1ck, dones, wt1 + 262144, outs + (size_t)jc * 131072,
                      h1st, c1st, jc, nsteps, (jc == 0) ? 1 : 0 };
        scan_k<<<256, 512, 0, stream>>>(sa1);
    }

    // ---------- head phase (row-chunked) ----------
    for (int r0 = 0; r0 < M_SEQ; r0 += RC) {
        const int rows = (M_SEQ - r0 < RC) ? (M_SEQ - r0) : RC;
        ushort_t* ph = (ushort_t*)S;
        ushort_t* pn = (ushort_t*)(S + (size_t)rows * 1024);
        ushort_t* mh = (ushort_t*)(S + (size_t)rows * 1536);
        ushort_t* sh = (ushort_t*)(S + (size_t)rows * 2560);
        // pred_hidden = relu([sf, action] @ Wf1^T + bf1)  [N=512, K=288]
        gemm_k<1, 1, ushort_t, float><<<dim3(rows / 128, 4), 256, 0, stream>>>(
            outs + (size_t)r0 * 256, action + (size_t)r0 * 32, Wf1_b, bf1, ph, 288, 512);
        // pred_next = pred_hidden @ Wf2^T + bf2           [N=256, K=512]
        gemm_k<0, 0, ushort_t, ushort_t><<<dim3(rows / 128, 2), 256, 0, stream>>>(
            ph, nullptr, Wf2_b, bf2, pn, 512, 256);
        // forward loss + intrinsic reward
        fl_k<<<rows / 4, 256, 0, stream>>>(pn, outs, (float*)d_out, accp, r0, out_size);
        // mh / sh = relu([sf, pred_next] @ W^T + b)       [N=512, K=512]
        gemm_k<2, 1, ushort_t, ushort_t><<<dim3(rows / 128, 4), 256, 0, stream>>>(
            outs + (size_t)r0 * 256, pn, Wm1_b, bm1, mh, 512, 512);
        gemm_k<2, 1, ushort_t, ushort_t><<<dim3(rows / 128, 4), 256, 0, stream>>>(
            outs + (size_t)r0 * 256, pn, Ws1_b, bs1, sh, 512, 512);
        // mu/std heads + inverse loss
        musd_k<<<rows / 8, 256, 0, stream>>>(mh, sh, W2t, bm2, bs2, action, accp + 1, r0);
    }

    // scalars + hidden
    fin_k<<<2048, 256, 0, stream>>>(accp, h0st, h1st, c0st, c1st, (float*)d_out, out_size);
}

// Round 10
// 7399.608 us; speedup vs baseline: 3.4886x; 1.0022x over previous
//
#include <hip/hip_runtime.h>
#include <hip/hip_bf16.h>

typedef unsigned short ushort_t;
typedef unsigned int   uint_t;

// Problem constants: T1=257, B=512, SD=128, AD=32, HS=512, SF=256, L=2
#define M_ALL 131584   // 257*512
#define M_SEQ 131072   // 256*512

// ---------- helpers ----------
__device__ __forceinline__ float bf2f(ushort_t u) {
    union { uint_t i; float f; } v; v.i = ((uint_t)u) << 16; return v.f;
}
__device__ __forceinline__ float asf(uint_t i) {
    union { uint_t u; float f; } v; v.u = i; return v.f;
}
__device__ __forceinline__ ushort_t f2bf(float f) {
    union { float f; uint_t i; } v; v.f = f;
    uint_t r = v.i + 0x7FFFu + ((v.i >> 16) & 1u);
    return (ushort_t)(r >> 16);
}
__device__ __forceinline__ float fsigm(float x) { return 1.f / (1.f + __expf(-x)); }
__device__ __forceinline__ float ftanh(float x) {
    x = fminf(15.f, fmaxf(-15.f, x));
    float e = __expf(2.f * x);
    return (e - 1.f) / (e + 1.f);
}

typedef __attribute__((ext_vector_type(8))) short  bfrag;   // 8 x bf16
typedef __attribute__((ext_vector_type(4))) float  ffrag;   // 4 x f32 accum

// stage 8 elements into LDS as bf16 (f32 source converts, bf16 source copies)
__device__ __forceinline__ void stage8(const float* p, ushort_t* dst) {
    const float4 a = *(const float4*)p;
    const float4 b = *(const float4*)(p + 4);
    bfrag v;
    v[0] = (short)f2bf(a.x); v[1] = (short)f2bf(a.y);
    v[2] = (short)f2bf(a.z); v[3] = (short)f2bf(a.w);
    v[4] = (short)f2bf(b.x); v[5] = (short)f2bf(b.y);
    v[6] = (short)f2bf(b.z); v[7] = (short)f2bf(b.w);
    *(bfrag*)dst = v;
}
__device__ __forceinline__ void stage8(const ushort_t* p, ushort_t* dst) {
    *(uint4*)dst = *(const uint4*)p;
}

// ---------- 128x128-tile bf16 MFMA GEMM: C = act(A @ W^T + bias), C bf16, W bf16, bias f32 ----------
// AMODE 0: plain A1 (stride K)
// AMODE 1: k<256 -> A1 stride 256 ; k>=256 -> A2 stride 32  (x = [sf, action])
// AMODE 2: k<256 -> A1 stride 256 ; k>=256 -> A2 stride 256 (xi = [sf, pred_next])
template<int AMODE, int ACT, typename TA1, typename TA2>
__global__ __launch_bounds__(256) void gemm_k(
    const TA1* __restrict__ A1, const TA2* __restrict__ A2,
    const ushort_t* __restrict__ W, const float* __restrict__ b1,
    ushort_t* __restrict__ C, int K, int N)
{
    __shared__ __align__(16) ushort_t As[128][40];
    __shared__ __align__(16) ushort_t Ws[128][40];

    const int tid  = threadIdx.x;
    const int m0   = blockIdx.x * 128;
    const int n0   = blockIdx.y * 128;
    const int lane = tid & 63;
    const int wv   = tid >> 6;
    const int wm   = (wv & 1) * 64;
    const int wn   = (wv >> 1) * 64;
    const int quad = lane >> 4;
    const int ln   = lane & 15;

    ffrag acc[4][4];
#pragma unroll
    for (int i = 0; i < 4; i++)
#pragma unroll
        for (int j = 0; j < 4; j++) acc[i][j] = (ffrag){0.f, 0.f, 0.f, 0.f};

    const int arow = tid >> 2;        // 0..63 (stages rows arow, arow+64)
    const int acol = (tid & 3) * 8;   // 0,8,16,24

    for (int k0 = 0; k0 < K; k0 += 32) {
        const int kk = k0 + acol;
#pragma unroll
        for (int rr = 0; rr < 2; rr++) {
            const int row = arow + rr * 64;
            if (AMODE == 0) {
                stage8(A1 + (size_t)(m0 + row) * K + kk, &As[row][acol]);
            } else if (AMODE == 1) {
                if (kk < 256) stage8(A1 + (size_t)(m0 + row) * 256 + kk, &As[row][acol]);
                else          stage8(A2 + (size_t)(m0 + row) * 32 + (kk - 256), &As[row][acol]);
            } else {
                if (kk < 256) stage8(A1 + (size_t)(m0 + row) * 256 + kk, &As[row][acol]);
                else          stage8(A2 + (size_t)(m0 + row) * 256 + (kk - 256), &As[row][acol]);
            }
            stage8(W + (size_t)(n0 + row) * K + kk, &Ws[row][acol]);
        }
        __syncthreads();

        bfrag af[4], bfv[4];
#pragma unroll
        for (int i = 0; i < 4; i++) af[i]  = *(const bfrag*)&As[wm + i * 16 + ln][quad * 8];
#pragma unroll
        for (int j = 0; j < 4; j++) bfv[j] = *(const bfrag*)&Ws[wn + j * 16 + ln][quad * 8];
#pragma unroll
        for (int i = 0; i < 4; i++)
#pragma unroll
            for (int j = 0; j < 4; j++)
                acc[i][j] = __builtin_amdgcn_mfma_f32_16x16x32_bf16(af[i], bfv[j], acc[i][j], 0, 0, 0);
        __syncthreads();
    }

#pragma unroll
    for (int j = 0; j < 4; j++) {
        const int n = n0 + wn + j * 16 + ln;
        const float bias = b1[n];
#pragma unroll
        for (int i = 0; i < 4; i++) {
#pragma unroll
            for (int r = 0; r < 4; r++) {
                const int m = m0 + wm + i * 16 + quad * 4 + r;
                float x = acc[i][j][r] + bias;
                if (ACT == 1) x = fmaxf(x, 0.f);
                C[(size_t)m * N + n] = f2bf(x);
            }
        }
    }
}

// ---------- prep: bf16 weights + gate-interleaved recurrent layouts ----------
struct PrepArgs {
    const float *Wfe, *Wih0, *Whh0, *bih0, *bhh0, *Wih1, *Whh1, *bih1, *bhh1;
    const float *Wf1, *Wf2, *Wm1, *Ws1, *Wm2, *Ws2;
    const float *bm1, *bs1;
    ushort_t *Wfe_b, *Wih0_b, *Wih1_b, *wt0, *wt1, *Wf1_b, *Wf2_b, *Wms_b;
    float *W2t, *bias0s, *bias1s, *bms;
};
__global__ __launch_bounds__(256) void prep_k(PrepArgs a)
{
    const int idx = blockIdx.x * 256 + threadIdx.x;
    const int stride = gridDim.x * 256;
    for (int e = idx; e < 65536; e += stride)  a.Wfe_b[e]  = f2bf(a.Wfe[e]);
    for (int e = idx; e < 524288; e += stride) a.Wih0_b[e] = f2bf(a.Wih0[e]);   // (1024,512)
    for (int e = idx; e < 262144; e += stride) a.Wih1_b[e] = f2bf(a.Wih1[e]);   // (1024,256)
    for (int e = idx; e < 262144; e += stride) {              // wt0
        const int k = e >> 10, q = e & 1023;
        const int s = q & 1, u = (q >> 1) & 255;
        const int j = ((q >> 9) << 9) + s * 256 + u;
        a.wt0[e] = f2bf(a.Whh0[j * 256 + k]);
    }
    for (int e = idx; e < 524288; e += stride) {              // wt1 (upper half = Whh1 interleave)
        const int k = e >> 10, q = e & 1023;
        const int s = q & 1, u = (q >> 1) & 255;
        const int j = ((q >> 9) << 9) + s * 256 + u;
        a.wt1[e] = f2bf((k < 256) ? a.Wih1[j * 256 + k] : a.Whh1[j * 256 + (k - 256)]);
    }
    for (int e = idx; e < 147456; e += stride) a.Wf1_b[e] = f2bf(a.Wf1[e]);
    for (int e = idx; e < 131072; e += stride) a.Wf2_b[e] = f2bf(a.Wf2[e]);
    for (int e = idx; e < 524288; e += stride) {              // Wms_b: (1024,512) = [Wm1; Ws1]
        const int n = e >> 9, k = e & 511;
        a.Wms_b[e] = f2bf((n < 512) ? a.Wm1[n * 512 + k] : a.Ws1[(n - 512) * 512 + k]);
    }
    for (int e = idx; e < 32768; e += stride) {               // W2t: (512,64) k-major f32
        const int k = e >> 6, c = e & 63;
        a.W2t[e] = (c < 32) ? a.Wm2[c * 512 + k] : a.Ws2[(c - 32) * 512 + k];
    }
    for (int e = idx; e < 1024; e += stride) {
        a.bias0s[e] = a.bih0[e] + a.bhh0[e];
        a.bias1s[e] = a.bih1[e] + a.bhh1[e];
        a.bms[e]    = (e < 512) ? a.bm1[e] : a.bs1[e - 512];
    }
}

// ---------- block-local LSTM scan (NO grid sync): one layer, 256 indep blocks ----------
struct ScanArgs {
    const ushort_t* xg;      // (nsteps*512, 1024) bf16, gate order {i,f,g,o}x256
    const int*      dones;   // (257,512) int32, absolute t indexing
    const ushort_t* wt;      // gate-interleaved recurrent weights (256 k-rows, 1024)
    ushort_t*       hout;    // bf16 h stream: (nsteps*512, 256), chunk-local s indexing
    float*          hst;     // persistent h (512*256 f32)
    float*          cst;     // persistent c (512*256 f32)
    int jc, nsteps, init;
};

__global__ __launch_bounds__(512) void scan_k(ScanArgs a)
{
    __shared__ __align__(16) float xs[2][264];
    const int tid = threadIdx.x;
    const int row = tid >> 8, u = tid & 255;
    const int b = blockIdx.x * 2 + row;
    float h = a.init ? 0.f : a.hst[b * 256 + u];
    float c = a.init ? 0.f : a.cst[b * 256 + u];
    const ushort_t* wtu = a.wt + 2 * u;

    for (int sst = 0; sst < a.nsteps; ++sst) {
        const int t = a.jc + sst;
        const float m = 1.f - (float)a.dones[t * 512 + b];
        xs[row][u] = h * m;
        __syncthreads();
        const size_t base = ((size_t)sst * 512 + b) * 1024;
        float ai = bf2f(a.xg[base + u]),       af = bf2f(a.xg[base + 256 + u]);
        float ag = bf2f(a.xg[base + 512 + u]), ao = bf2f(a.xg[base + 768 + u]);
        for (int k0 = 0; k0 < 256; k0 += 8) {
            uint_t pif[8], pgo[8];
#pragma unroll
            for (int e = 0; e < 8; e++) {
                pif[e] = *(const uint_t*)(wtu + ((k0 + e) << 10));
                pgo[e] = *(const uint_t*)(wtu + ((k0 + e) << 10) + 512);
            }
            float hr[8];
            *(float4*)&hr[0] = *(const float4*)&xs[row][k0];
            *(float4*)&hr[4] = *(const float4*)&xs[row][k0 + 4];
#pragma unroll
            for (int e = 0; e < 8; e++) {
                const float wi = asf(pif[e] << 16), wf = asf(pif[e] & 0xFFFF0000u);
                const float wg = asf(pgo[e] << 16), wo = asf(pgo[e] & 0xFFFF0000u);
                ai += hr[e] * wi; af += hr[e] * wf; ag += hr[e] * wg; ao += hr[e] * wo;
            }
        }
        const float cold = c * m;
        const float c2 = fsigm(af) * cold + fsigm(ai) * ftanh(ag);
        const float h2 = fsigm(ao) * ftanh(c2);
        c = c2; h = h2;
        a.hout[((size_t)sst * 512 + b) * 256 + u] = f2bf(h2);
        __syncthreads();
    }
    a.hst[b * 256 + u] = h;
    a.cst[b * 256 + u] = c;
}

// ---------- forward loss + intrinsic reward (row-chunked), f32 out ----------
__global__ __launch_bounds__(256) void fl_k(const ushort_t* __restrict__ pn,
                                            const ushort_t* __restrict__ outs,
                                            float* __restrict__ out, float* __restrict__ acc,
                                            int r0, int out_size)
{
    __shared__ float bs[4];
    const int tid = threadIdx.x;
    const int w = tid >> 6, l = tid & 63;
    const size_t rl = (size_t)blockIdx.x * 4 + w;
    const size_t rg = rl + r0;
    const ushort_t* p = pn + rl * 256;
    const ushort_t* q = outs + (rg + 512) * 256;   // next_state_features = outs[t+1]
    float s = 0.f;
#pragma unroll
    for (int i = 0; i < 4; i++) {
        const float d = bf2f(p[l + i * 64]) - bf2f(q[l + i * 64]);
        s += d * d;
    }
#pragma unroll
    for (int off = 32; off > 0; off >>= 1) s += __shfl_down(s, off);
    if (l == 0) { if ((long long)(2 + rg) < out_size) out[2 + rg] = s; bs[w] = s; }
    __syncthreads();
    if (tid == 0) atomicAdd(acc, bs[0] + bs[1] + bs[2] + bs[3]);
}

// ---------- fused mu/std heads + inverse loss (row-chunked), packed msh ----------
__global__ __launch_bounds__(256) void musd_k(
    const ushort_t* __restrict__ msh,    // (rows, 1024): [mh | sh]
    const float* __restrict__ W2t, const float* __restrict__ bm2,
    const float* __restrict__ bs2, const float* __restrict__ action,
    float* __restrict__ acc, int r0)
{
    __shared__ __align__(16) ushort_t mhs[8][512];
    __shared__ __align__(16) ushort_t shs[8][512];
    __shared__ float red[256];
    const int tid = threadIdx.x;
    const size_t rl0 = (size_t)blockIdx.x * 8;
    for (int i = tid; i < 512; i += 256) {
        const int row = i >> 6, c = (i & 63) * 8;
        *(uint4*)&mhs[row][c] = *(const uint4*)&msh[(rl0 + row) * 1024 + c];
        *(uint4*)&shs[row][c] = *(const uint4*)&msh[(rl0 + row) * 1024 + 512 + c];
    }
    __syncthreads();
    const int row = tid >> 5, c = tid & 31;
    float am = bm2[c], asv = bs2[c];
    for (int k = 0; k < 512; k += 8) {
#pragma unroll
        for (int e = 0; e < 8; e++) {
            const float wm = W2t[(k + e) * 64 + c];
            const float wsv = W2t[(k + e) * 64 + 32 + c];
            am  += bf2f(mhs[row][k + e]) * wm;
            asv += bf2f(shs[row][k + e]) * wsv;
        }
    }
    const float mu = ftanh(am);
    const float sp = fmaxf(asv, 0.f) + log1pf(__expf(-fabsf(asv)));   // softplus
    const float a  = action[(rl0 + r0 + row) * 32 + c];
    const float z  = (a - mu) / sp;
    red[tid] = 0.5f * z * z + __logf(sp) + 0.918938533204672741f;     // -log_prob
    __syncthreads();
    for (int s = 128; s > 0; s >>= 1) { if (tid < s) red[tid] += red[tid + s]; __syncthreads(); }
    if (tid == 0) atomicAdd(acc, red[0]);
}

// ---------- finalize: scalar losses + hidden copy-out (f32) ----------
__global__ __launch_bounds__(256) void fin_k(const float* __restrict__ acc,
                                             const float* __restrict__ h0st,
                                             const float* __restrict__ h1st,
                                             const float* __restrict__ c0st,
                                             const float* __restrict__ c1st,
                                             float* __restrict__ out, int out_size)
{
    const size_t idx = (size_t)blockIdx.x * 256 + threadIdx.x;
    if (idx == 0 && out_size > 0) out[0] = acc[0] / 33554432.f;   // mean over 256*512*256
    if (idx == 1 && out_size > 1) out[1] = acc[1] / 4194304.f;    // mean over 256*512*32
    if (idx < 524288) {
        const int which = (int)(idx >> 17);
        const int local = (int)(idx & 131071);
        float v;
        if      (which == 0) v = h0st[local];
        else if (which == 1) v = h1st[local];
        else if (which == 2) v = c0st[local];
        else                 v = c1st[local];
        const size_t o = 2 + 131072 + idx;
        if ((long long)o < out_size) out[o] = v;
    }
}

extern "C" void kernel_launch(void* const* d_in, const int* in_sizes, int n_in,
                              void* d_out, int out_size, void* d_ws, size_t ws_size,
                              hipStream_t stream)
{
    const float* states = (const float*)d_in[0];
    const float* action = (const float*)d_in[1];
    const int*   dones  = (const int*)d_in[2];
    const float* Wfe  = (const float*)d_in[3];
    const float* bfe  = (const float*)d_in[4];
    const float* Wih0 = (const float*)d_in[5];
    const float* Whh0 = (const float*)d_in[6];
    const float* bih0 = (const float*)d_in[7];
    const float* bhh0 = (const float*)d_in[8];
    const float* Wih1 = (const float*)d_in[9];
    const float* Whh1 = (const float*)d_in[10];
    const float* bih1 = (const float*)d_in[11];
    const float* bhh1 = (const float*)d_in[12];
    const float* Wf1  = (const float*)d_in[13];
    const float* bf1  = (const float*)d_in[14];
    const float* Wf2  = (const float*)d_in[15];
    const float* bf2  = (const float*)d_in[16];
    const float* Wm1  = (const float*)d_in[17];
    const float* bm1  = (const float*)d_in[18];
    const float* Wm2  = (const float*)d_in[19];
    const float* bm2  = (const float*)d_in[20];
    const float* Ws1  = (const float*)d_in[21];
    const float* bs1  = (const float*)d_in[22];
    const float* Ws2  = (const float*)d_in[23];
    const float* bs2  = (const float*)d_in[24];

    // ---------- workspace layout (persistent region) ----------
    char* ws = (char*)d_ws;
    size_t off = 0;
    ushort_t* outs    = (ushort_t*)(ws + off); off += 67371008;  // 257*512*256 bf16
    float*    h0st    = (float*)(ws + off);    off += 524288;
    float*    c0st    = (float*)(ws + off);    off += 524288;
    float*    h1st    = (float*)(ws + off);    off += 524288;
    float*    c1st    = (float*)(ws + off);    off += 524288;
    ushort_t* wt0     = (ushort_t*)(ws + off); off += 524288;
    ushort_t* wt1     = (ushort_t*)(ws + off); off += 1048576;
    ushort_t* Wfe_b   = (ushort_t*)(ws + off); off += 131072;
    ushort_t* Wih0_b  = (ushort_t*)(ws + off); off += 1048576;
    ushort_t* Wih1_b  = (ushort_t*)(ws + off); off += 524288;
    ushort_t* Wf1_b   = (ushort_t*)(ws + off); off += 294912;
    ushort_t* Wf2_b   = (ushort_t*)(ws + off); off += 262144;
    ushort_t* Wms_b   = (ushort_t*)(ws + off); off += 1048576;
    float*    W2t     = (float*)(ws + off);    off += 131072;
    float*    bias0s  = (float*)(ws + off);    off += 4096;
    float*    bias1s  = (float*)(ws + off);    off += 4096;
    float*    bms     = (float*)(ws + off);    off += 4096;
    float*    accp    = (float*)(ws + off);    off += 256;
    char*     S       = ws + off;              // chunk scratch
    const size_t avail = (ws_size > off) ? (ws_size - off) : 0;

    // scan-phase chunk: per step feats 524288 + xg0 1048576 + h0s 262144 + xg1 1048576 B.
    // TC capped at 40 so the chunk working set (~115 MB) stays L3-resident.
    const size_t STEP_B = 2883584;
    int TC = (int)(avail / STEP_B);
    if (TC > 40) TC = 40;
    if (TC < 1)  TC = 1;
    // head-phase chunk: per row ph(1024)+pn(512)+msh(2048) = 3584 B; cap 24576 rows (~88 MB).
    long long rc = (long long)(avail / 3584) & ~127LL;
    if (rc > 24576) rc = 24576;
    if (rc < 128)   rc = 128;
    const int RC = (int)rc;

    hipMemsetAsync(accp, 0, 256, stream);

    PrepArgs pa{ Wfe, Wih0, Whh0, bih0, bhh0, Wih1, Whh1, bih1, bhh1,
                 Wf1, Wf2, Wm1, Ws1, Wm2, Ws2, bm1, bs1,
                 Wfe_b, Wih0_b, Wih1_b, wt0, wt1, Wf1_b, Wf2_b, Wms_b,
                 W2t, bias0s, bias1s, bms };
    prep_k<<<512, 256, 0, stream>>>(pa);

    // ---------- scan phase (time-chunked, L3-resident chunks) ----------
    ushort_t* featsck = (ushort_t*)S;
    ushort_t* xg0ck   = (ushort_t*)(S + (size_t)TC * 524288);
    ushort_t* h0sck   = (ushort_t*)(S + (size_t)TC * 1572864);
    ushort_t* xg1ck   = (ushort_t*)(S + (size_t)TC * 1835008);
    for (int jc = 0; jc < 257; jc += TC) {
        const int nsteps = (257 - jc < TC) ? (257 - jc) : TC;
        // feats = relu(states_chunk @ Wfe^T + bfe)      [N=512, K=128]
        gemm_k<0, 1, float, float><<<dim3(nsteps * 4, 4), 256, 0, stream>>>(
            states + (size_t)jc * 512 * 128, nullptr, Wfe_b, bfe, featsck, 128, 512);
        // xg0 = feats @ Wih0^T + (bih0 + bhh0)          [N=1024, K=512]
        gemm_k<0, 0, ushort_t, ushort_t><<<dim3(nsteps * 4, 8), 256, 0, stream>>>(
            featsck, nullptr, Wih0_b, bias0s, xg0ck, 512, 1024);
        // layer-0 scan
        ScanArgs sa0{ xg0ck, dones, wt0, h0sck, h0st, c0st, jc, nsteps, (jc == 0) ? 1 : 0 };
        scan_k<<<256, 512, 0, stream>>>(sa0);
        // xg1 = h0s @ Wih1^T + (bih1 + bhh1)            [N=1024, K=256]
        gemm_k<0, 0, ushort_t, ushort_t><<<dim3(nsteps * 4, 8), 256, 0, stream>>>(
            h0sck, nullptr, Wih1_b, bias1s, xg1ck, 256, 1024);
        // layer-1 scan
        ScanArgs sa1{ xg1ck, dones, wt1 + 262144, outs + (size_t)jc * 131072,
                      h1st, c1st, jc, nsteps, (jc == 0) ? 1 : 0 };
        scan_k<<<256, 512, 0, stream>>>(sa1);
    }

    // ---------- head phase (row-chunked, L3-resident chunks) ----------
    for (int r0 = 0; r0 < M_SEQ; r0 += RC) {
        const int rows = (M_SEQ - r0 < RC) ? (M_SEQ - r0) : RC;
        ushort_t* ph  = (ushort_t*)S;
        ushort_t* pn  = (ushort_t*)(S + (size_t)rows * 1024);
        ushort_t* msh = (ushort_t*)(S + (size_t)rows * 1536);
        // pred_hidden = relu([sf, action] @ Wf1^T + bf1)  [N=512, K=288]
        gemm_k<1, 1, ushort_t, float><<<dim3(rows / 128, 4), 256, 0, stream>>>(
            outs + (size_t)r0 * 256, action + (size_t)r0 * 32, Wf1_b, bf1, ph, 288, 512);
        // pred_next = pred_hidden @ Wf2^T + bf2           [N=256, K=512]
        gemm_k<0, 0, ushort_t, ushort_t><<<dim3(rows / 128, 2), 256, 0, stream>>>(
            ph, nullptr, Wf2_b, bf2, pn, 512, 256);
        // forward loss + intrinsic reward
        fl_k<<<rows / 4, 256, 0, stream>>>(pn, outs, (float*)d_out, accp, r0, out_size);
        // msh = relu([sf, pred_next] @ [Wm1;Ws1]^T + [bm1;bs1])  [N=1024, K=512]
        gemm_k<2, 1, ushort_t, ushort_t><<<dim3(rows / 128, 8), 256, 0, stream>>>(
            outs + (size_t)r0 * 256, pn, Wms_b, bms, msh, 512, 1024);
        // mu/std heads + inverse loss
        musd_k<<<rows / 8, 256, 0, stream>>>(msh, W2t, bm2, bs2, action, accp + 1, r0);
    }

    // scalars + hidden
    fin_k<<<2048, 256, 0, stream>>>(accp, h0st, h1st, c0st, c1st, (float*)d_out, out_size);
}

// Round 11
// 7369.933 us; speedup vs baseline: 3.5027x; 1.0040x over previous
//
#include <hip/hip_runtime.h>
#include <hip/hip_bf16.h>

typedef unsigned short ushort_t;
typedef unsigned int   uint_t;

// Problem constants: T1=257, B=512, SD=128, AD=32, HS=512, SF=256, L=2
#define M_ALL 131584   // 257*512
#define M_SEQ 131072   // 256*512

// ---------- helpers ----------
__device__ __forceinline__ float bf2f(ushort_t u) {
    union { uint_t i; float f; } v; v.i = ((uint_t)u) << 16; return v.f;
}
__device__ __forceinline__ float asf(uint_t i) {
    union { uint_t u; float f; } v; v.u = i; return v.f;
}
__device__ __forceinline__ ushort_t f2bf(float f) {
    union { float f; uint_t i; } v; v.f = f;
    uint_t r = v.i + 0x7FFFu + ((v.i >> 16) & 1u);
    return (ushort_t)(r >> 16);
}
__device__ __forceinline__ float fsigm(float x) { return 1.f / (1.f + __expf(-x)); }
__device__ __forceinline__ float ftanh(float x) {
    x = fminf(15.f, fmaxf(-15.f, x));
    float e = __expf(2.f * x);
    return (e - 1.f) / (e + 1.f);
}

typedef __attribute__((ext_vector_type(8))) short  bfrag;   // 8 x bf16
typedef __attribute__((ext_vector_type(4))) float  ffrag;   // 4 x f32 accum

// stage 8 elements into LDS as bf16 (f32 source converts, bf16 source copies)
__device__ __forceinline__ void stage8(const float* p, ushort_t* dst) {
    const float4 a = *(const float4*)p;
    const float4 b = *(const float4*)(p + 4);
    bfrag v;
    v[0] = (short)f2bf(a.x); v[1] = (short)f2bf(a.y);
    v[2] = (short)f2bf(a.z); v[3] = (short)f2bf(a.w);
    v[4] = (short)f2bf(b.x); v[5] = (short)f2bf(b.y);
    v[6] = (short)f2bf(b.z); v[7] = (short)f2bf(b.w);
    *(bfrag*)dst = v;
}
__device__ __forceinline__ void stage8(const ushort_t* p, ushort_t* dst) {
    *(uint4*)dst = *(const uint4*)p;
}

// ---------- 128x128-tile bf16 MFMA GEMM: C = act(A @ W^T + bias), C bf16, W bf16, bias f32 ----------
// AMODE 0: plain A1 (stride K)
// AMODE 1: k<256 -> A1 stride 256 ; k>=256 -> A2 stride 32  (x = [sf, action])
// AMODE 2: k<256 -> A1 stride 256 ; k>=256 -> A2 stride 256 (xi = [sf, pred_next])
template<int AMODE, int ACT, typename TA1, typename TA2>
__global__ __launch_bounds__(256) void gemm_k(
    const TA1* __restrict__ A1, const TA2* __restrict__ A2,
    const ushort_t* __restrict__ W, const float* __restrict__ b1,
    ushort_t* __restrict__ C, int K, int N)
{
    __shared__ __align__(16) ushort_t As[128][40];
    __shared__ __align__(16) ushort_t Ws[128][40];

    const int tid  = threadIdx.x;
    const int m0   = blockIdx.x * 128;
    const int n0   = blockIdx.y * 128;
    const int lane = tid & 63;
    const int wv   = tid >> 6;
    const int wm   = (wv & 1) * 64;
    const int wn   = (wv >> 1) * 64;
    const int quad = lane >> 4;
    const int ln   = lane & 15;

    ffrag acc[4][4];
#pragma unroll
    for (int i = 0; i < 4; i++)
#pragma unroll
        for (int j = 0; j < 4; j++) acc[i][j] = (ffrag){0.f, 0.f, 0.f, 0.f};

    const int arow = tid >> 2;        // 0..63 (stages rows arow, arow+64)
    const int acol = (tid & 3) * 8;   // 0,8,16,24

    for (int k0 = 0; k0 < K; k0 += 32) {
        const int kk = k0 + acol;
#pragma unroll
        for (int rr = 0; rr < 2; rr++) {
            const int row = arow + rr * 64;
            if (AMODE == 0) {
                stage8(A1 + (size_t)(m0 + row) * K + kk, &As[row][acol]);
            } else if (AMODE == 1) {
                if (kk < 256) stage8(A1 + (size_t)(m0 + row) * 256 + kk, &As[row][acol]);
                else          stage8(A2 + (size_t)(m0 + row) * 32 + (kk - 256), &As[row][acol]);
            } else {
                if (kk < 256) stage8(A1 + (size_t)(m0 + row) * 256 + kk, &As[row][acol]);
                else          stage8(A2 + (size_t)(m0 + row) * 256 + (kk - 256), &As[row][acol]);
            }
            stage8(W + (size_t)(n0 + row) * K + kk, &Ws[row][acol]);
        }
        __syncthreads();

        bfrag af[4], bfv[4];
#pragma unroll
        for (int i = 0; i < 4; i++) af[i]  = *(const bfrag*)&As[wm + i * 16 + ln][quad * 8];
#pragma unroll
        for (int j = 0; j < 4; j++) bfv[j] = *(const bfrag*)&Ws[wn + j * 16 + ln][quad * 8];
#pragma unroll
        for (int i = 0; i < 4; i++)
#pragma unroll
            for (int j = 0; j < 4; j++)
                acc[i][j] = __builtin_amdgcn_mfma_f32_16x16x32_bf16(af[i], bfv[j], acc[i][j], 0, 0, 0);
        __syncthreads();
    }

#pragma unroll
    for (int j = 0; j < 4; j++) {
        const int n = n0 + wn + j * 16 + ln;
        const float bias = b1[n];
#pragma unroll
        for (int i = 0; i < 4; i++) {
#pragma unroll
            for (int r = 0; r < 4; r++) {
                const int m = m0 + wm + i * 16 + quad * 4 + r;
                float x = acc[i][j][r] + bias;
                if (ACT == 1) x = fmaxf(x, 0.f);
                C[(size_t)m * N + n] = f2bf(x);
            }
        }
    }
}

// ---------- prep: bf16 weights + gate-interleaved recurrent layouts ----------
struct PrepArgs {
    const float *Wfe, *Wih0, *Whh0, *bih0, *bhh0, *Wih1, *Whh1, *bih1, *bhh1;
    const float *Wf1, *Wf2, *Wm1, *Ws1, *Wm2, *Ws2;
    const float *bm1, *bs1;
    ushort_t *Wfe_b, *Wih0_b, *Wih1_b, *wt0, *wt1, *Wf1_b, *Wf2_b, *Wms_b;
    float *W2t, *bias0s, *bias1s, *bms;
};
__global__ __launch_bounds__(256) void prep_k(PrepArgs a)
{
    const int idx = blockIdx.x * 256 + threadIdx.x;
    const int stride = gridDim.x * 256;
    for (int e = idx; e < 65536; e += stride)  a.Wfe_b[e]  = f2bf(a.Wfe[e]);
    for (int e = idx; e < 524288; e += stride) a.Wih0_b[e] = f2bf(a.Wih0[e]);   // (1024,512)
    for (int e = idx; e < 262144; e += stride) a.Wih1_b[e] = f2bf(a.Wih1[e]);   // (1024,256)
    for (int e = idx; e < 262144; e += stride) {              // wt0
        const int k = e >> 10, q = e & 1023;
        const int s = q & 1, u = (q >> 1) & 255;
        const int j = ((q >> 9) << 9) + s * 256 + u;
        a.wt0[e] = f2bf(a.Whh0[j * 256 + k]);
    }
    for (int e = idx; e < 524288; e += stride) {              // wt1 (upper half = Whh1 interleave)
        const int k = e >> 10, q = e & 1023;
        const int s = q & 1, u = (q >> 1) & 255;
        const int j = ((q >> 9) << 9) + s * 256 + u;
        a.wt1[e] = f2bf((k < 256) ? a.Wih1[j * 256 + k] : a.Whh1[j * 256 + (k - 256)]);
    }
    for (int e = idx; e < 147456; e += stride) a.Wf1_b[e] = f2bf(a.Wf1[e]);
    for (int e = idx; e < 131072; e += stride) a.Wf2_b[e] = f2bf(a.Wf2[e]);
    for (int e = idx; e < 524288; e += stride) {              // Wms_b: (1024,512) = [Wm1; Ws1]
        const int n = e >> 9, k = e & 511;
        a.Wms_b[e] = f2bf((n < 512) ? a.Wm1[n * 512 + k] : a.Ws1[(n - 512) * 512 + k]);
    }
    for (int e = idx; e < 32768; e += stride) {               // W2t: (512,64) k-major f32
        const int k = e >> 6, c = e & 63;
        a.W2t[e] = (c < 32) ? a.Wm2[c * 512 + k] : a.Ws2[(c - 32) * 512 + k];
    }
    for (int e = idx; e < 1024; e += stride) {
        a.bias0s[e] = a.bih0[e] + a.bhh0[e];
        a.bias1s[e] = a.bih1[e] + a.bhh1[e];
        a.bms[e]    = (e < 512) ? a.bm1[e] : a.bs1[e - 512];
    }
}

// ---------- block-local LSTM scan (NO grid sync): one layer, 256 indep blocks ----------
struct ScanArgs {
    const ushort_t* xg;      // (nsteps*512, 1024) bf16, gate order {i,f,g,o}x256
    const int*      dones;   // (257,512) int32, absolute t indexing
    const ushort_t* wt;      // gate-interleaved recurrent weights (256 k-rows, 1024)
    ushort_t*       hout;    // bf16 h stream: (nsteps*512, 256), chunk-local s indexing
    float*          hst;     // persistent h (512*256 f32)
    float*          cst;     // persistent c (512*256 f32)
    int jc, nsteps, init;
};

__global__ __launch_bounds__(512) void scan_k(ScanArgs a)
{
    __shared__ __align__(16) float xs[2][264];
    const int tid = threadIdx.x;
    const int row = tid >> 8, u = tid & 255;
    const int b = blockIdx.x * 2 + row;
    float h = a.init ? 0.f : a.hst[b * 256 + u];
    float c = a.init ? 0.f : a.cst[b * 256 + u];
    const ushort_t* wtu = a.wt + 2 * u;

    for (int sst = 0; sst < a.nsteps; ++sst) {
        const int t = a.jc + sst;
        const float m = 1.f - (float)a.dones[t * 512 + b];
        xs[row][u] = h * m;
        __syncthreads();
        const size_t base = ((size_t)sst * 512 + b) * 1024;
        float ai = bf2f(a.xg[base + u]),       af = bf2f(a.xg[base + 256 + u]);
        float ag = bf2f(a.xg[base + 512 + u]), ao = bf2f(a.xg[base + 768 + u]);
        for (int k0 = 0; k0 < 256; k0 += 8) {
            uint_t pif[8], pgo[8];
#pragma unroll
            for (int e = 0; e < 8; e++) {
                pif[e] = *(const uint_t*)(wtu + ((k0 + e) << 10));
                pgo[e] = *(const uint_t*)(wtu + ((k0 + e) << 10) + 512);
            }
            float hr[8];
            *(float4*)&hr[0] = *(const float4*)&xs[row][k0];
            *(float4*)&hr[4] = *(const float4*)&xs[row][k0 + 4];
#pragma unroll
            for (int e = 0; e < 8; e++) {
                const float wi = asf(pif[e] << 16), wf = asf(pif[e] & 0xFFFF0000u);
                const float wg = asf(pgo[e] << 16), wo = asf(pgo[e] & 0xFFFF0000u);
                ai += hr[e] * wi; af += hr[e] * wf; ag += hr[e] * wg; ao += hr[e] * wo;
            }
        }
        const float cold = c * m;
        const float c2 = fsigm(af) * cold + fsigm(ai) * ftanh(ag);
        const float h2 = fsigm(ao) * ftanh(c2);
        c = c2; h = h2;
        a.hout[((size_t)sst * 512 + b) * 256 + u] = f2bf(h2);
        __syncthreads();
    }
    a.hst[b * 256 + u] = h;
    a.cst[b * 256 + u] = c;
}

// ---------- forward loss + intrinsic reward (row-chunked), f32 out ----------
__global__ __launch_bounds__(256) void fl_k(const ushort_t* __restrict__ pn,
                                            const ushort_t* __restrict__ outs,
                                            float* __restrict__ out, float* __restrict__ acc,
                                            int r0, int out_size)
{
    __shared__ float bs[4];
    const int tid = threadIdx.x;
    const int w = tid >> 6, l = tid & 63;
    const size_t rl = (size_t)blockIdx.x * 4 + w;
    const size_t rg = rl + r0;
    const ushort_t* p = pn + rl * 256;
    const ushort_t* q = outs + (rg + 512) * 256;   // next_state_features = outs[t+1]
    float s = 0.f;
#pragma unroll
    for (int i = 0; i < 4; i++) {
        const float d = bf2f(p[l + i * 64]) - bf2f(q[l + i * 64]);
        s += d * d;
    }
#pragma unroll
    for (int off = 32; off > 0; off >>= 1) s += __shfl_down(s, off);
    if (l == 0) { if ((long long)(2 + rg) < out_size) out[2 + rg] = s; bs[w] = s; }
    __syncthreads();
    if (tid == 0) atomicAdd(acc, bs[0] + bs[1] + bs[2] + bs[3]);
}

// ---------- fused mu/std heads + inverse loss (row-chunked), packed msh ----------
__global__ __launch_bounds__(256) void musd_k(
    const ushort_t* __restrict__ msh,    // (rows, 1024): [mh | sh]
    const float* __restrict__ W2t, const float* __restrict__ bm2,
    const float* __restrict__ bs2, const float* __restrict__ action,
    float* __restrict__ acc, int r0)
{
    __shared__ __align__(16) ushort_t mhs[8][512];
    __shared__ __align__(16) ushort_t shs[8][512];
    __shared__ float red[256];
    const int tid = threadIdx.x;
    const size_t rl0 = (size_t)blockIdx.x * 8;
    for (int i = tid; i < 512; i += 256) {
        const int row = i >> 6, c = (i & 63) * 8;
        *(uint4*)&mhs[row][c] = *(const uint4*)&msh[(rl0 + row) * 1024 + c];
        *(uint4*)&shs[row][c] = *(const uint4*)&msh[(rl0 + row) * 1024 + 512 + c];
    }
    __syncthreads();
    const int row = tid >> 5, c = tid & 31;
    float am = bm2[c], asv = bs2[c];
    for (int k = 0; k < 512; k += 8) {
#pragma unroll
        for (int e = 0; e < 8; e++) {
            const float wm = W2t[(k + e) * 64 + c];
            const float wsv = W2t[(k + e) * 64 + 32 + c];
            am  += bf2f(mhs[row][k + e]) * wm;
            asv += bf2f(shs[row][k + e]) * wsv;
        }
    }
    const float mu = ftanh(am);
    const float sp = fmaxf(asv, 0.f) + log1pf(__expf(-fabsf(asv)));   // softplus
    const float a  = action[(rl0 + r0 + row) * 32 + c];
    const float z  = (a - mu) / sp;
    red[tid] = 0.5f * z * z + __logf(sp) + 0.918938533204672741f;     // -log_prob
    __syncthreads();
    for (int s = 128; s > 0; s >>= 1) { if (tid < s) red[tid] += red[tid + s]; __syncthreads(); }
    if (tid == 0) atomicAdd(acc, red[0]);
}

// ---------- finalize: scalar losses + hidden copy-out (f32) ----------
__global__ __launch_bounds__(256) void fin_k(const float* __restrict__ acc,
                                             const float* __restrict__ h0st,
                                             const float* __restrict__ h1st,
                                             const float* __restrict__ c0st,
                                             const float* __restrict__ c1st,
                                             float* __restrict__ out, int out_size)
{
    const size_t idx = (size_t)blockIdx.x * 256 + threadIdx.x;
    if (idx == 0 && out_size > 0) out[0] = acc[0] / 33554432.f;   // mean over 256*512*256
    if (idx == 1 && out_size > 1) out[1] = acc[1] / 4194304.f;    // mean over 256*512*32
    if (idx < 524288) {
        const int which = (int)(idx >> 17);
        const int local = (int)(idx & 131071);
        float v;
        if      (which == 0) v = h0st[local];
        else if (which == 1) v = h1st[local];
        else if (which == 2) v = c0st[local];
        else                 v = c1st[local];
        const size_t o = 2 + 131072 + idx;
        if ((long long)o < out_size) out[o] = v;
    }
}

extern "C" void kernel_launch(void* const* d_in, const int* in_sizes, int n_in,
                              void* d_out, int out_size, void* d_ws, size_t ws_size,
                              hipStream_t stream)
{
    const float* states = (const float*)d_in[0];
    const float* action = (const float*)d_in[1];
    const int*   dones  = (const int*)d_in[2];
    const float* Wfe  = (const float*)d_in[3];
    const float* bfe  = (const float*)d_in[4];
    const float* Wih0 = (const float*)d_in[5];
    const float* Whh0 = (const float*)d_in[6];
    const float* bih0 = (const float*)d_in[7];
    const float* bhh0 = (const float*)d_in[8];
    const float* Wih1 = (const float*)d_in[9];
    const float* Whh1 = (const float*)d_in[10];
    const float* bih1 = (const float*)d_in[11];
    const float* bhh1 = (const float*)d_in[12];
    const float* Wf1  = (const float*)d_in[13];
    const float* bf1  = (const float*)d_in[14];
    const float* Wf2  = (const float*)d_in[15];
    const float* bf2  = (const float*)d_in[16];
    const float* Wm1  = (const float*)d_in[17];
    const float* bm1  = (const float*)d_in[18];
    const float* Wm2  = (const float*)d_in[19];
    const float* bm2  = (const float*)d_in[20];
    const float* Ws1  = (const float*)d_in[21];
    const float* bs1  = (const float*)d_in[22];
    const float* Ws2  = (const float*)d_in[23];
    const float* bs2  = (const float*)d_in[24];

    // ---------- workspace layout (persistent region) ----------
    char* ws = (char*)d_ws;
    size_t off = 0;
    ushort_t* outs    = (ushort_t*)(ws + off); off += 67371008;  // 257*512*256 bf16
    float*    h0st    = (float*)(ws + off);    off += 524288;
    float*    c0st    = (float*)(ws + off);    off += 524288;
    float*    h1st    = (float*)(ws + off);    off += 524288;
    float*    c1st    = (float*)(ws + off);    off += 524288;
    ushort_t* wt0     = (ushort_t*)(ws + off); off += 524288;
    ushort_t* wt1     = (ushort_t*)(ws + off); off += 1048576;
    ushort_t* Wfe_b   = (ushort_t*)(ws + off); off += 131072;
    ushort_t* Wih0_b  = (ushort_t*)(ws + off); off += 1048576;
    ushort_t* Wih1_b  = (ushort_t*)(ws + off); off += 524288;
    ushort_t* Wf1_b   = (ushort_t*)(ws + off); off += 294912;
    ushort_t* Wf2_b   = (ushort_t*)(ws + off); off += 262144;
    ushort_t* Wms_b   = (ushort_t*)(ws + off); off += 1048576;
    float*    W2t     = (float*)(ws + off);    off += 131072;
    float*    bias0s  = (float*)(ws + off);    off += 4096;
    float*    bias1s  = (float*)(ws + off);    off += 4096;
    float*    bms     = (float*)(ws + off);    off += 4096;
    float*    accp    = (float*)(ws + off);    off += 256;
    char*     S       = ws + off;              // chunk scratch
    const size_t avail = (ws_size > off) ? (ws_size - off) : 0;

    // scan-phase chunk: per step feats 524288 + xg0 1048576 + h0s 262144 + xg1 1048576 B.
    // TC as large as workspace allows: scan dispatches carry a ~400 µs fixed cost, so
    // minimize their count (R9/R10 A/B: 2 dispatches @257 steps = 1.6 ms vs 14 @40 = 6.1 ms).
    const size_t STEP_B = 2883584;
    int TC = (int)(avail / STEP_B);
    if (TC > 257) TC = 257;
    if (TC < 1)  TC = 1;
    // head-phase chunk: per row ph(1024)+pn(512)+msh(2048) = 3584 B; cap 24576 rows (~88 MB)
    // so head intermediates stay L3-resident (R10: head 5.8 -> ~0.7 ms).
    long long rc = (long long)(avail / 3584) & ~127LL;
    if (rc > 24576) rc = 24576;
    if (rc < 128)   rc = 128;
    const int RC = (int)rc;

    hipMemsetAsync(accp, 0, 256, stream);

    PrepArgs pa{ Wfe, Wih0, Whh0, bih0, bhh0, Wih1, Whh1, bih1, bhh1,
                 Wf1, Wf2, Wm1, Ws1, Wm2, Ws2, bm1, bs1,
                 Wfe_b, Wih0_b, Wih1_b, wt0, wt1, Wf1_b, Wf2_b, Wms_b,
                 W2t, bias0s, bias1s, bms };
    prep_k<<<512, 256, 0, stream>>>(pa);

    // ---------- scan phase (max-size chunks: minimize scan dispatch count) ----------
    ushort_t* featsck = (ushort_t*)S;
    ushort_t* xg0ck   = (ushort_t*)(S + (size_t)TC * 524288);
    ushort_t* h0sck   = (ushort_t*)(S + (size_t)TC * 1572864);
    ushort_t* xg1ck   = (ushort_t*)(S + (size_t)TC * 1835008);
    for (int jc = 0; jc < 257; jc += TC) {
        const int nsteps = (257 - jc < TC) ? (257 - jc) : TC;
        // feats = relu(states_chunk @ Wfe^T + bfe)      [N=512, K=128]
        gemm_k<0, 1, float, float><<<dim3(nsteps * 4, 4), 256, 0, stream>>>(
            states + (size_t)jc * 512 * 128, nullptr, Wfe_b, bfe, featsck, 128, 512);
        // xg0 = feats @ Wih0^T + (bih0 + bhh0)          [N=1024, K=512]
        gemm_k<0, 0, ushort_t, ushort_t><<<dim3(nsteps * 4, 8), 256, 0, stream>>>(
            featsck, nullptr, Wih0_b, bias0s, xg0ck, 512, 1024);
        // layer-0 scan
        ScanArgs sa0{ xg0ck, dones, wt0, h0sck, h0st, c0st, jc, nsteps, (jc == 0) ? 1 : 0 };
        scan_k<<<256, 512, 0, stream>>>(sa0);
        // xg1 = h0s @ Wih1^T + (bih1 + bhh1)            [N=1024, K=256]
        gemm_k<0, 0, ushort_t, ushort_t><<<dim3(nsteps * 4, 8), 256, 0, stream>>>(
            h0sck, nullptr, Wih1_b, bias1s, xg1ck, 256, 1024);
        // layer-1 scan
        ScanArgs sa1{ xg1ck, dones, wt1 + 262144, outs + (size_t)jc * 131072,
                      h1st, c1st, jc, nsteps, (jc == 0) ? 1 : 0 };
        scan_k<<<256, 512, 0, stream>>>(sa1);
    }

    // ---------- head phase (row-chunked, L3-resident chunks) ----------
    for (int r0 = 0; r0 < M_SEQ; r0 += RC) {
        const int rows = (M_SEQ - r0 < RC) ? (M_SEQ - r0) : RC;
        ushort_t* ph  = (ushort_t*)S;
        ushort_t* pn  = (ushort_t*)(S + (size_t)rows * 1024);
        ushort_t* msh = (ushort_t*)(S + (size_t)rows * 1536);
        // pred_hidden = relu([sf, action] @ Wf1^T + bf1)  [N=512, K=288]
        gemm_k<1, 1, ushort_t, float><<<dim3(rows / 128, 4), 256, 0, stream>>>(
            outs + (size_t)r0 * 256, action + (size_t)r0 * 32, Wf1_b, bf1, ph, 288, 512);
        // pred_next = pred_hidden @ Wf2^T + bf2           [N=256, K=512]
        gemm_k<0, 0, ushort_t, ushort_t><<<dim3(rows / 128, 2), 256, 0, stream>>>(
            ph, nullptr, Wf2_b, bf2, pn, 512, 256);
        // forward loss + intrinsic reward
        fl_k<<<rows / 4, 256, 0, stream>>>(pn, outs, (float*)d_out, accp, r0, out_size);
        // msh = relu([sf, pred_next] @ [Wm1;Ws1]^T + [bm1;bs1])  [N=1024, K=512]
        gemm_k<2, 1, ushort_t, ushort_t><<<dim3(rows / 128, 8), 256, 0, stream>>>(
            outs + (size_t)r0 * 256, pn, Wms_b, bms, msh, 512, 1024);
        // mu/std heads + inverse loss
        musd_k<<<rows / 8, 256, 0, stream>>>(msh, W2t, bm2, bs2, action, accp + 1, r0);
    }

    // scalars + hidden
    fin_k<<<2048, 256, 0, stream>>>(accp, h0st, h1st, c0st, c1st, (float*)d_out, out_size);
}